// Round 3
// baseline (111.534 us; speedup 1.0000x reference)
//
#include <hip/hip_runtime.h>
#include <hip/hip_bf16.h>

typedef __bf16 bf16x8 __attribute__((ext_vector_type(8)));
typedef __bf16 bf16x4 __attribute__((ext_vector_type(4)));
typedef float f32x4 __attribute__((ext_vector_type(4)));

#define S_LEN 2048
#define D_DIM 64
#define NQT   (S_LEN / 64)   // 32 q-tiles of 64 rows

// Flash-attention fwd, causal, bf16 MFMA, fp32 I/O.
// Block = 256 threads (4 waves); ONE 64-row q-tile per block (max parallelism:
// 1024 blocks = 4096 waves). Causal imbalance handled by LPT ordering:
// blockIdx.x=0 -> longest tile (qt=31) launches first, short tiles backfill.
// K/V staged via register prefetch into double-buffered LDS; 1 barrier/k-tile.
__global__ __launch_bounds__(256) void attn_fwd_kernel(
    const float* __restrict__ Vg, const float* __restrict__ Qg,
    const float* __restrict__ Kg, float* __restrict__ Og) {
  __shared__ __align__(16) unsigned char k_lds[2][64 * 128];   // 16 KB  [k][d] bf16
  __shared__ __align__(16) unsigned char vt_lds[2][64 * 128];  // 16 KB  [d][k] bf16
  __shared__ __align__(16) unsigned char p_lds[4][16 * 128];   // 8 KB   per-wave [q][k]

  const int tid  = threadIdx.x;
  const int lane = tid & 63;
  const int w    = tid >> 6;   // wave 0..3
  const int lr   = lane & 15;
  const int lg   = lane >> 4;  // 0..3
  const int d_   = tid & 63;   // V-stage: d column
  const int kb   = tid >> 6;   // V-stage: k-block 0..3 (and +4)

  const int qt   = NQT - 1 - blockIdx.x;   // LPT: longest first
  const int bh   = blockIdx.y;
  const long base = (long)bh * (S_LEN * D_DIM);
  const int q0   = qt * 64;

  // ---- Q fragment, pre-scaled by 1/8 (exact pow2) ----
  bf16x8 qf[2];
  {
    const float* qp = Qg + base + (q0 + w * 16 + lr) * D_DIM + lg * 8;
    #pragma unroll
    for (int c = 0; c < 2; ++c) {
      float4 f0 = *reinterpret_cast<const float4*>(qp + c * 32);
      float4 f1 = *reinterpret_cast<const float4*>(qp + c * 32 + 4);
      bf16x8 t;
      t[0]=(__bf16)(f0.x*0.125f); t[1]=(__bf16)(f0.y*0.125f);
      t[2]=(__bf16)(f0.z*0.125f); t[3]=(__bf16)(f0.w*0.125f);
      t[4]=(__bf16)(f1.x*0.125f); t[5]=(__bf16)(f1.y*0.125f);
      t[6]=(__bf16)(f1.z*0.125f); t[7]=(__bf16)(f1.w*0.125f);
      qf[c] = t;
    }
  }

  // ones B-frag: row-sum of P lands in col 0 of the accumulator
  bf16x8 onesf;
  #pragma unroll
  for (int j = 0; j < 8; ++j) onesf[j] = (lr == 0) ? (__bf16)1.0f : (__bf16)0.0f;

  f32x4 po[4], pl;
  float m_i[4];
  #pragma unroll
  for (int j = 0; j < 4; ++j) { po[j] = (f32x4){0.f,0.f,0.f,0.f}; m_i[j] = -1e30f; }
  pl = (f32x4){0.f,0.f,0.f,0.f};

  // ---- staging: global -> regs (prefetch), regs -> LDS (bf16, swizzled) ----
  float4 kreg[4];
  float  vreg[16];

  auto load_regs = [&](int kt) {
    const float* kg = Kg + base + kt * (64 * D_DIM);
    #pragma unroll
    for (int i = 0; i < 4; ++i) {
      int idx = tid + 256 * i;
      int r = idx >> 4, f4 = idx & 15;
      kreg[i] = *reinterpret_cast<const float4*>(kg + r * 64 + f4 * 4);
    }
    const float* vg = Vg + base + kt * (64 * D_DIM);
    #pragma unroll
    for (int j = 0; j < 8; ++j) {
      vreg[j]     = vg[(kb * 8 + j) * 64 + d_];
      vreg[8 + j] = vg[((kb + 4) * 8 + j) * 64 + d_];
    }
  };

  auto write_buf = [&](int sel) {
    unsigned char* kl = k_lds[sel];
    unsigned char* vl = vt_lds[sel];
    #pragma unroll
    for (int i = 0; i < 4; ++i) {
      int idx = tid + 256 * i;
      int r = idx >> 4, f4 = idx & 15;
      bf16x4 t;
      t[0]=(__bf16)kreg[i].x; t[1]=(__bf16)kreg[i].y;
      t[2]=(__bf16)kreg[i].z; t[3]=(__bf16)kreg[i].w;
      int b = r * 128 + f4 * 8;
      b ^= (r & 7) << 4;
      *reinterpret_cast<bf16x4*>(&kl[b]) = t;
    }
    bf16x8 t0, t1;
    #pragma unroll
    for (int j = 0; j < 8; ++j) { t0[j] = (__bf16)vreg[j]; t1[j] = (__bf16)vreg[8+j]; }
    int b0 = d_ * 128 + kb * 16;        b0 ^= (d_ & 7) << 4;
    int b1 = d_ * 128 + (kb + 4) * 16;  b1 ^= (d_ & 7) << 4;
    *reinterpret_cast<bf16x8*>(&vl[b0]) = t0;
    *reinterpret_cast<bf16x8*>(&vl[b1]) = t1;
  };

  // ---- main loop: one barrier per k-tile ----
  load_regs(0);
  write_buf(0);
  __syncthreads();

  for (int kt = 0; kt <= qt; ++kt) {
    int sel = kt & 1;
    if (kt < qt) load_regs(kt + 1);

    const unsigned char* kl = k_lds[sel];
    const unsigned char* vl = vt_lds[sel];

    // ---- S = Q K^T (scale pre-folded into Q) ----
    f32x4 s_acc[4];
    #pragma unroll
    for (int ct = 0; ct < 4; ++ct) s_acc[ct] = (f32x4){0.f,0.f,0.f,0.f};
    __builtin_amdgcn_s_setprio(1);
    #pragma unroll
    for (int ct = 0; ct < 4; ++ct) {
      #pragma unroll
      for (int c = 0; c < 2; ++c) {
        int r = ct * 16 + lr;
        int b = r * 128 + c * 64 + lg * 16;
        b ^= (r & 7) << 4;
        bf16x8 kf = *reinterpret_cast<const bf16x8*>(&kl[b]);
        s_acc[ct] = __builtin_amdgcn_mfma_f32_16x16x32_bf16(qf[c], kf, s_acc[ct], 0, 0, 0);
      }
    }
    __builtin_amdgcn_s_setprio(0);

    // ---- mask + row max ----
    const bool diag = (kt == qt);
    float tmax[4] = {-1e30f,-1e30f,-1e30f,-1e30f};
    #pragma unroll
    for (int ct = 0; ct < 4; ++ct) {
      #pragma unroll
      for (int j = 0; j < 4; ++j) {
        float s = s_acc[ct][j];
        if (diag && (kt * 64 + ct * 16 + lr) > (q0 + w * 16 + lg * 4 + j)) s = -1e30f;
        s_acc[ct][j] = s;
        tmax[j] = fmaxf(tmax[j], s);
      }
    }
    #pragma unroll
    for (int off = 1; off < 16; off <<= 1) {
      #pragma unroll
      for (int j = 0; j < 4; ++j)
        tmax[j] = fmaxf(tmax[j], __shfl_xor(tmax[j], off));
    }
    float alpha[4];
    #pragma unroll
    for (int j = 0; j < 4; ++j) {
      float mn = fmaxf(m_i[j], tmax[j]);
      alpha[j] = __expf(m_i[j] - mn);
      m_i[j] = mn;
    }
    // ---- P = exp(S - m) -> per-wave LDS (bf16, swizzled) ----
    #pragma unroll
    for (int ct = 0; ct < 4; ++ct) {
      #pragma unroll
      for (int j = 0; j < 4; ++j) {
        float p = __expf(s_acc[ct][j] - m_i[j]);
        int row = lg * 4 + j;
        int col = ct * 16 + lr;
        int b = row * 128 + col * 2;
        b ^= (row & 7) << 4;
        *reinterpret_cast<__bf16*>(&p_lds[w][b]) = (__bf16)p;
      }
    }
    // ---- rescale accumulators ----
    #pragma unroll
    for (int j = 0; j < 4; ++j) {
      pl[j] *= alpha[j];
      #pragma unroll
      for (int dt = 0; dt < 4; ++dt) po[dt][j] *= alpha[j];
    }
    // ---- O += P V ; l += P * ones ----
    __builtin_amdgcn_s_setprio(1);
    #pragma unroll
    for (int c = 0; c < 2; ++c) {
      int ab = lr * 128 + c * 64 + lg * 16;
      ab ^= (lr & 7) << 4;
      bf16x8 pa = *reinterpret_cast<const bf16x8*>(&p_lds[w][ab]);
      pl = __builtin_amdgcn_mfma_f32_16x16x32_bf16(pa, onesf, pl, 0, 0, 0);
      #pragma unroll
      for (int dt = 0; dt < 4; ++dt) {
        int vrow = dt * 16 + lr;
        int bb = vrow * 128 + c * 64 + lg * 16;
        bb ^= (vrow & 7) << 4;
        bf16x8 vb = *reinterpret_cast<const bf16x8*>(&vl[bb]);
        po[dt] = __builtin_amdgcn_mfma_f32_16x16x32_bf16(pa, vb, po[dt], 0, 0, 0);
      }
    }
    __builtin_amdgcn_s_setprio(0);

    if (kt < qt) write_buf(sel ^ 1);
    __syncthreads();
  }

  // ---- epilogue: normalize and store fp32 ----
  #pragma unroll
  for (int j = 0; j < 4; ++j) {
    float lv  = __shfl(pl[j], lane & 48);   // col 0 of the 16-lane group
    float inv = 1.0f / lv;
    int row = q0 + w * 16 + lg * 4 + j;
    #pragma unroll
    for (int dt = 0; dt < 4; ++dt)
      Og[base + row * D_DIM + dt * 16 + lr] = po[dt][j] * inv;
  }
}

extern "C" void kernel_launch(void* const* d_in, const int* in_sizes, int n_in,
                              void* d_out, int out_size, void* d_ws, size_t ws_size,
                              hipStream_t stream) {
  const float* V = (const float*)d_in[0];
  const float* Q = (const float*)d_in[1];
  const float* K = (const float*)d_in[2];
  float* O = (float*)d_out;
  int bh = in_sizes[0] / (S_LEN * D_DIM);  // B*H = 32
  dim3 grid(NQT, bh);
  attn_fwd_kernel<<<grid, 256, 0, stream>>>(V, Q, K, O);
}

// Round 5
// 91.330 us; speedup vs baseline: 1.2212x; 1.2212x over previous
//
#include <hip/hip_runtime.h>
#include <hip/hip_bf16.h>

typedef __bf16 bf16x8 __attribute__((ext_vector_type(8)));
typedef __bf16 bf16x4 __attribute__((ext_vector_type(4)));
typedef float f32x4 __attribute__((ext_vector_type(4)));

#define S_LEN 2048
#define D_DIM 64
#define NQT   32

// Flash-attention fwd, causal, bf16 MFMA, fp32 I/O.
// Swapped QK^T (mfma(K,Q)) -> lane holds a 16-wide slice of its q-row's P:
// softmax is 15 in-lane fmax + 2 shuffles. Single-buffered K/V LDS (24 KB)
// + register-carried prefetch. exp2-domain softmax, scale folded into Q.
// NOTE: every LDS address is row*128 + ((col_bytes) ^ ((row&7)<<4)) with
// col_bytes <= 127 -- the XOR swizzle must wrap the FULL intra-row offset
// (adding c*64 outside the XOR carries into the row bits: round-4 bug).
__global__ __launch_bounds__(256) void attn_fwd_kernel(
    const float* __restrict__ Vg, const float* __restrict__ Qg,
    const float* __restrict__ Kg, float* __restrict__ Og) {
  __shared__ __align__(16) unsigned char k_lds[64 * 128];    // 8 KB [k][d] bf16
  __shared__ __align__(16) unsigned char vt_lds[64 * 128];   // 8 KB [d][k] bf16
  __shared__ __align__(16) unsigned char p_lds[4][16 * 128]; // 8 KB per-wave [q][k]

  const int tid  = threadIdx.x;
  const int lane = tid & 63;
  const int w    = tid >> 6;   // wave 0..3
  const int lr   = lane & 15;
  const int lg   = lane >> 4;  // 0..3
  const int swz  = (lr & 7) << 4;

  // ---- block decode: XCD-clustered bh (4 bh per XCD -> K/V fits one L2),
  //      long/short qt interleaved for drain balance ----
  const int lb = blockIdx.x;            // 0..1023
  const int e  = lb & 7;                // XCD (round-robin dispatch assumption)
  const int s  = lb >> 3;               // 0..127
  const int bh = e + 8 * (s >> 5);      // 4 bh per XCD cluster
  const int qs = s & 31;
  const int qt = (qs & 1) ? (NQT - 1 - (qs >> 1)) : (qs >> 1);
  const long base = (long)bh * (S_LEN * D_DIM);
  const int q0 = qt * 64;

  // ---- Q fragment (B-operand), prescaled by 1/8 * log2(e) ----
  bf16x8 qf[2];
  {
    const float qsc = 0.125f * 1.44269504f;
    const float* qp = Qg + base + (q0 + w * 16 + lr) * D_DIM + lg * 8;
    #pragma unroll
    for (int c = 0; c < 2; ++c) {
      float4 f0 = *reinterpret_cast<const float4*>(qp + c * 32);
      float4 f1 = *reinterpret_cast<const float4*>(qp + c * 32 + 4);
      bf16x8 t;
      t[0]=(__bf16)(f0.x*qsc); t[1]=(__bf16)(f0.y*qsc);
      t[2]=(__bf16)(f0.z*qsc); t[3]=(__bf16)(f0.w*qsc);
      t[4]=(__bf16)(f1.x*qsc); t[5]=(__bf16)(f1.y*qsc);
      t[6]=(__bf16)(f1.z*qsc); t[7]=(__bf16)(f1.w*qsc);
      qf[c] = t;
    }
  }

  // ones B-frag: col 0 of PV-ones accumulator = row sum of P
  bf16x8 onesf;
  #pragma unroll
  for (int j = 0; j < 8; ++j) onesf[j] = (lr == 0) ? (__bf16)1.0f : (__bf16)0.0f;

  f32x4 po[4], pl;
  float m_run = -1e30f;
  #pragma unroll
  for (int j = 0; j < 4; ++j) po[j] = (f32x4){0.f,0.f,0.f,0.f};
  pl = (f32x4){0.f,0.f,0.f,0.f};

  // ---- staging: global -> regs (prefetch), regs -> LDS bf16 swizzled ----
  float4 kreg[4];
  float  vreg[16];
  const int d_ = lane;        // V stage: d column
  const int kb = w;           // V stage: k-block

  auto load_regs = [&](int kt) {
    const float* kg = Kg + base + kt * (64 * D_DIM);
    #pragma unroll
    for (int i = 0; i < 4; ++i) {
      int idx = tid + 256 * i;
      int r = idx >> 4, f4 = idx & 15;
      kreg[i] = *reinterpret_cast<const float4*>(kg + r * 64 + f4 * 4);
    }
    const float* vg = Vg + base + kt * (64 * D_DIM);
    #pragma unroll
    for (int j = 0; j < 8; ++j) {
      vreg[j]     = vg[(kb * 8 + j) * 64 + d_];
      vreg[8 + j] = vg[((kb + 4) * 8 + j) * 64 + d_];
    }
  };

  auto write_buf = [&]() {
    #pragma unroll
    for (int i = 0; i < 4; ++i) {
      int idx = tid + 256 * i;
      int r = idx >> 4, f4 = idx & 15;
      bf16x4 t;
      t[0]=(__bf16)kreg[i].x; t[1]=(__bf16)kreg[i].y;
      t[2]=(__bf16)kreg[i].z; t[3]=(__bf16)kreg[i].w;
      int b = r * 128 + ((f4 * 8) ^ ((r & 7) << 4));
      *reinterpret_cast<bf16x4*>(&k_lds[b]) = t;
    }
    bf16x8 t0, t1;
    #pragma unroll
    for (int j = 0; j < 8; ++j) { t0[j] = (__bf16)vreg[j]; t1[j] = (__bf16)vreg[8+j]; }
    int b0 = d_ * 128 + ((kb * 16) ^ ((d_ & 7) << 4));
    int b1 = d_ * 128 + (((kb + 4) * 16) ^ ((d_ & 7) << 4));
    *reinterpret_cast<bf16x8*>(&vt_lds[b0]) = t0;
    *reinterpret_cast<bf16x8*>(&vt_lds[b1]) = t1;
  };

  // ---- main loop ----
  load_regs(0);
  write_buf();
  __syncthreads();

  for (int kt = 0; kt <= qt; ++kt) {
    const bool last = (kt == qt);
    if (!last) load_regs(kt + 1);   // issue next-tile global loads early

    // S^T via mfma(K, Q): sa[ct][j] = S[q = w*16+lr][k = ct*16 + lg*4 + j]
    f32x4 sa[4];
    #pragma unroll
    for (int ct = 0; ct < 4; ++ct) sa[ct] = (f32x4){0.f,0.f,0.f,0.f};
    __builtin_amdgcn_s_setprio(1);
    #pragma unroll
    for (int ct = 0; ct < 4; ++ct) {
      #pragma unroll
      for (int c = 0; c < 2; ++c) {
        int b = (ct * 16 + lr) * 128 + ((lg * 16 + c * 64) ^ swz);
        bf16x8 kf = *reinterpret_cast<const bf16x8*>(&k_lds[b]);
        sa[ct] = __builtin_amdgcn_mfma_f32_16x16x32_bf16(kf, qf[c], sa[ct], 0, 0, 0);
      }
    }
    __builtin_amdgcn_s_setprio(0);

    if (last) {  // causal mask on diag tile: k_loc > q_loc
      #pragma unroll
      for (int ct = 0; ct < 4; ++ct)
        #pragma unroll
        for (int j = 0; j < 4; ++j)
          if (ct * 16 + lg * 4 + j > w * 16 + lr) sa[ct][j] = -1e30f;
    }

    // row max: 15 in-lane fmax + 2 shuffles (across lg groups)
    float rmax = sa[0][0];
    #pragma unroll
    for (int ct = 0; ct < 4; ++ct)
      #pragma unroll
      for (int j = 0; j < 4; ++j) rmax = fmaxf(rmax, sa[ct][j]);
    rmax = fmaxf(rmax, __shfl_xor(rmax, 16));
    rmax = fmaxf(rmax, __shfl_xor(rmax, 32));

    float mn    = fmaxf(m_run, rmax);
    float alpha = exp2f(m_run - mn);
    m_run = mn;

    // P = exp2(S' - m') -> per-wave LDS row q=lr (b64 packed writes)
    #pragma unroll
    for (int ct = 0; ct < 4; ++ct) {
      bf16x4 t;
      #pragma unroll
      for (int j = 0; j < 4; ++j) t[j] = (__bf16)exp2f(sa[ct][j] - mn);
      int b = lr * 128 + ((ct * 32 + lg * 8) ^ swz);
      *reinterpret_cast<bf16x4*>(&p_lds[w][b]) = t;
    }

    // rescale accumulators: alpha for row q = lg*4+j via in-group shuffle
    float aj[4];
    #pragma unroll
    for (int j = 0; j < 4; ++j) aj[j] = __shfl(alpha, (lane & 48) | (lg * 4 + j));
    #pragma unroll
    for (int j = 0; j < 4; ++j) {
      pl[j] *= aj[j];
      #pragma unroll
      for (int dt = 0; dt < 4; ++dt) po[dt][j] *= aj[j];
    }

    // O += P V ; l += P * ones
    __builtin_amdgcn_s_setprio(1);
    #pragma unroll
    for (int c = 0; c < 2; ++c) {
      int ab = lr * 128 + ((lg * 16 + c * 64) ^ swz);
      bf16x8 pa = *reinterpret_cast<const bf16x8*>(&p_lds[w][ab]);
      pl = __builtin_amdgcn_mfma_f32_16x16x32_bf16(pa, onesf, pl, 0, 0, 0);
      #pragma unroll
      for (int dt = 0; dt < 4; ++dt) {
        int vb_ = (dt * 16 + lr) * 128 + ((lg * 16 + c * 64) ^ swz);
        bf16x8 vb = *reinterpret_cast<const bf16x8*>(&vt_lds[vb_]);
        po[dt] = __builtin_amdgcn_mfma_f32_16x16x32_bf16(pa, vb, po[dt], 0, 0, 0);
      }
    }
    __builtin_amdgcn_s_setprio(0);

    if (!last) {
      __syncthreads();   // all waves done reading K/V
      write_buf();       // overwrite with tile kt+1 (vmcnt waits land here)
      __syncthreads();   // writes visible
    }
  }

  // ---- epilogue: normalize, store fp32 ----
  #pragma unroll
  for (int j = 0; j < 4; ++j) {
    float lv  = __shfl(pl[j], lane & 48);   // col-0 lane of own 16-group
    float inv = 1.0f / lv;
    int row = q0 + w * 16 + lg * 4 + j;
    #pragma unroll
    for (int dt = 0; dt < 4; ++dt)
      Og[base + row * D_DIM + dt * 16 + lr] = po[dt][j] * inv;
  }
}

extern "C" void kernel_launch(void* const* d_in, const int* in_sizes, int n_in,
                              void* d_out, int out_size, void* d_ws, size_t ws_size,
                              hipStream_t stream) {
  const float* V = (const float*)d_in[0];
  const float* Q = (const float*)d_in[1];
  const float* K = (const float*)d_in[2];
  float* O = (float*)d_out;
  attn_fwd_kernel<<<dim3(1024), dim3(256), 0, stream>>>(V, Q, K, O);
}

// Round 6
// 87.782 us; speedup vs baseline: 1.2706x; 1.0404x over previous
//
#include <hip/hip_runtime.h>
#include <hip/hip_bf16.h>

typedef __bf16 bf16x8 __attribute__((ext_vector_type(8)));
typedef __bf16 bf16x4 __attribute__((ext_vector_type(4)));
typedef float f32x4 __attribute__((ext_vector_type(4)));

#define S_LEN 2048
#define D_DIM 64
#define NQT   32

// async global->LDS, 16B per lane; lds dest = wave-uniform base + lane*16
#define GLOAD16(gp, lp)                                              \
  __builtin_amdgcn_global_load_lds(                                  \
      (const __attribute__((address_space(1))) void*)(gp),           \
      (__attribute__((address_space(3))) void*)(lp), 16, 0, 0)

// ---------------- preprocess: K -> bf16 swizzled-image, V -> V^T bf16 ----------------
// Output per (bh,kt) tile: 8192-byte block whose byte b = row*128 + swz_col is the
// EXACT LDS image the main kernel wants (swizzle: col ^ ((row&7)<<4), col<=127).
__global__ __launch_bounds__(256) void preprocess_kernel(
    const float* __restrict__ Kg, const float* __restrict__ Vg,
    unsigned char* __restrict__ Kb, unsigned char* __restrict__ Vt) {
  __shared__ float vt_f[64 * 64];  // 16 KB fp32 [k][d]
  const int tid  = threadIdx.x;
  const int tile = blockIdx.x;     // bh*32 + kt
  const float* kg = Kg + (long)tile * 4096;
  const float* vg = Vg + (long)tile * 4096;
  unsigned char* kb = Kb + (long)tile * 8192;
  unsigned char* vt = Vt + (long)tile * 8192;

  // K: task (r, c8): 8 consecutive d -> one swizzle-aligned 16B chunk
  #pragma unroll
  for (int i = 0; i < 2; ++i) {
    int task = tid + 256 * i;
    int r = task >> 3, c8 = task & 7;
    float4 a = *reinterpret_cast<const float4*>(kg + r * 64 + c8 * 8);
    float4 b = *reinterpret_cast<const float4*>(kg + r * 64 + c8 * 8 + 4);
    bf16x8 t;
    t[0]=(__bf16)a.x; t[1]=(__bf16)a.y; t[2]=(__bf16)a.z; t[3]=(__bf16)a.w;
    t[4]=(__bf16)b.x; t[5]=(__bf16)b.y; t[6]=(__bf16)b.z; t[7]=(__bf16)b.w;
    *reinterpret_cast<bf16x8*>(kb + r * 128 + ((c8 * 16) ^ ((r & 7) << 4))) = t;
  }
  // V: coalesced copy into LDS, then column-gather for the transpose
  #pragma unroll
  for (int i = 0; i < 4; ++i) {
    int task = tid + 256 * i;   // 1024 float4 tasks over 4096 floats
    *reinterpret_cast<float4*>(vt_f + task * 4) =
        *reinterpret_cast<const float4*>(vg + task * 4);
  }
  __syncthreads();
  #pragma unroll
  for (int i = 0; i < 2; ++i) {
    int task = tid + 256 * i;
    int d = task >> 3, k8 = task & 7;
    bf16x8 t;
    #pragma unroll
    for (int j = 0; j < 8; ++j) t[j] = (__bf16)vt_f[(k8 * 8 + j) * 64 + d];
    *reinterpret_cast<bf16x8*>(vt + d * 128 + ((k8 * 16) ^ ((d & 7) << 4))) = t;
  }
}

// ---------------- main: flash-attn fwd, causal; K/V staged via global_load_lds ----------------
__global__ __launch_bounds__(256) void attn_fwd_fast(
    const float* __restrict__ Qg, const unsigned char* __restrict__ Kb,
    const unsigned char* __restrict__ Vt, float* __restrict__ Og) {
  __shared__ __align__(16) unsigned char k_lds[2][8192];
  __shared__ __align__(16) unsigned char vt_lds[2][8192];
  __shared__ __align__(16) unsigned char p_lds[4][2048];

  const int tid  = threadIdx.x;
  const int lane = tid & 63;
  const int w    = tid >> 6;
  const int lr   = lane & 15;
  const int lg   = lane >> 4;
  const int swz  = (lr & 7) << 4;

  // XCD-clustered bh + long/short interleave (round-5 decode, kept)
  const int lb = blockIdx.x;
  const int e  = lb & 7;
  const int s  = lb >> 3;
  const int bh = e + 8 * (s >> 5);
  const int qs = s & 31;
  const int qt = (qs & 1) ? (NQT - 1 - (qs >> 1)) : (qs >> 1);
  const long base = (long)bh * (S_LEN * D_DIM);
  const int q0 = qt * 64;

  // Q fragment (B-operand), prescaled by 1/8 * log2(e)
  bf16x8 qf[2];
  {
    const float qsc = 0.125f * 1.44269504f;
    const float* qp = Qg + base + (q0 + w * 16 + lr) * D_DIM + lg * 8;
    #pragma unroll
    for (int c = 0; c < 2; ++c) {
      float4 f0 = *reinterpret_cast<const float4*>(qp + c * 32);
      float4 f1 = *reinterpret_cast<const float4*>(qp + c * 32 + 4);
      bf16x8 t;
      t[0]=(__bf16)(f0.x*qsc); t[1]=(__bf16)(f0.y*qsc);
      t[2]=(__bf16)(f0.z*qsc); t[3]=(__bf16)(f0.w*qsc);
      t[4]=(__bf16)(f1.x*qsc); t[5]=(__bf16)(f1.y*qsc);
      t[6]=(__bf16)(f1.z*qsc); t[7]=(__bf16)(f1.w*qsc);
      qf[c] = t;
    }
  }

  f32x4 po[4];
  #pragma unroll
  for (int j = 0; j < 4; ++j) po[j] = (f32x4){0.f,0.f,0.f,0.f};
  float m_run = -1e30f;   // per-lane == per-q-row (swapped layout)
  float l_run = 0.f;

  const unsigned char* kb_bh = Kb + ((long)bh << 5) * 8192;
  const unsigned char* vt_bh = Vt + ((long)bh << 5) * 8192;

  auto stage = [&](int kt, int sel) {
    const unsigned char* kp = kb_bh + (long)kt * 8192 + w * 2048 + lane * 16;
    const unsigned char* vp = vt_bh + (long)kt * 8192 + w * 2048 + lane * 16;
    unsigned char* kl = &k_lds[sel][w * 2048];
    unsigned char* vl = &vt_lds[sel][w * 2048];
    GLOAD16(kp,        kl);
    GLOAD16(kp + 1024, kl + 1024);
    GLOAD16(vp,        vl);
    GLOAD16(vp + 1024, vl + 1024);
  };

  stage(0, 0);
  __syncthreads();

  for (int kt = 0; kt <= qt; ++kt) {
    const int  sel  = kt & 1;
    const bool last = (kt == qt);
    if (!last) stage(kt + 1, sel ^ 1);  // async, lands before next barrier

    const unsigned char* kl = k_lds[sel];
    const unsigned char* vl = vt_lds[sel];

    // S^T via mfma(K, Q): sa[ct][j] = S[q = w*16+lr][k = ct*16 + lg*4 + j]
    f32x4 sa[4];
    #pragma unroll
    for (int ct = 0; ct < 4; ++ct) sa[ct] = (f32x4){0.f,0.f,0.f,0.f};
    __builtin_amdgcn_s_setprio(1);
    #pragma unroll
    for (int ct = 0; ct < 4; ++ct) {
      #pragma unroll
      for (int c = 0; c < 2; ++c) {
        int b = (ct * 16 + lr) * 128 + ((lg * 16 + c * 64) ^ swz);
        bf16x8 kf = *reinterpret_cast<const bf16x8*>(&kl[b]);
        sa[ct] = __builtin_amdgcn_mfma_f32_16x16x32_bf16(kf, qf[c], sa[ct], 0, 0, 0);
      }
    }
    __builtin_amdgcn_s_setprio(0);

    if (last) {  // causal mask, diag tile only
      #pragma unroll
      for (int ct = 0; ct < 4; ++ct)
        #pragma unroll
        for (int j = 0; j < 4; ++j)
          if (ct * 16 + lg * 4 + j > w * 16 + lr) sa[ct][j] = -1e30f;
    }

    // row max: 15 in-lane fmax + 2 shuffles
    float rmax = sa[0][0];
    #pragma unroll
    for (int ct = 0; ct < 4; ++ct)
      #pragma unroll
      for (int j = 0; j < 4; ++j) rmax = fmaxf(rmax, sa[ct][j]);
    rmax = fmaxf(rmax, __shfl_xor(rmax, 16));
    rmax = fmaxf(rmax, __shfl_xor(rmax, 32));

    // defer-max (T13): rescale only when the running max grew by > 8 (exp2 units)
    if (__any(rmax > m_run + 8.0f)) {
      float mn    = fmaxf(m_run, rmax);
      float alpha = exp2f(m_run - mn);
      m_run = mn;
      l_run *= alpha;
      float aj[4];
      #pragma unroll
      for (int j = 0; j < 4; ++j) aj[j] = __shfl(alpha, (lane & 48) | (lg * 4 + j));
      #pragma unroll
      for (int j = 0; j < 4; ++j)
        #pragma unroll
        for (int dt = 0; dt < 4; ++dt) po[dt][j] *= aj[j];
    }

    // P = exp2(S' - m) -> per-wave LDS row lr; fp32 row-sum in-lane
    float rowsum = 0.f;
    #pragma unroll
    for (int ct = 0; ct < 4; ++ct) {
      bf16x4 t;
      #pragma unroll
      for (int j = 0; j < 4; ++j) {
        float p = exp2f(sa[ct][j] - m_run);
        rowsum += p;
        t[j] = (__bf16)p;
      }
      int b = lr * 128 + ((ct * 32 + lg * 8) ^ swz);
      *reinterpret_cast<bf16x4*>(&p_lds[w][b]) = t;
    }
    rowsum += __shfl_xor(rowsum, 16);
    rowsum += __shfl_xor(rowsum, 32);
    l_run += rowsum;

    // O += P V
    __builtin_amdgcn_s_setprio(1);
    #pragma unroll
    for (int c = 0; c < 2; ++c) {
      int ab = lr * 128 + ((lg * 16 + c * 64) ^ swz);
      bf16x8 pa = *reinterpret_cast<const bf16x8*>(&p_lds[w][ab]);
      #pragma unroll
      for (int dt = 0; dt < 4; ++dt) {
        int vb_ = (dt * 16 + lr) * 128 + ((lg * 16 + c * 64) ^ swz);
        bf16x8 vb = *reinterpret_cast<const bf16x8*>(&vl[vb_]);
        po[dt] = __builtin_amdgcn_mfma_f32_16x16x32_bf16(pa, vb, po[dt], 0, 0, 0);
      }
    }
    __builtin_amdgcn_s_setprio(0);

    __syncthreads();  // drains vmcnt: next tile landed; all waves done with buf[sel]
  }

  // epilogue: normalize, store fp32
  #pragma unroll
  for (int j = 0; j < 4; ++j) {
    float lv  = __shfl(l_run, (lane & 48) | (lg * 4 + j));
    float inv = 1.0f / lv;
    int row = q0 + w * 16 + lg * 4 + j;
    #pragma unroll
    for (int dt = 0; dt < 4; ++dt)
      Og[base + row * D_DIM + dt * 16 + lr] = po[dt][j] * inv;
  }
}

// ---------------- fallback (round-5 kernel) if ws too small ----------------
__global__ __launch_bounds__(256) void attn_fwd_fallback(
    const float* __restrict__ Vg, const float* __restrict__ Qg,
    const float* __restrict__ Kg, float* __restrict__ Og) {
  __shared__ __align__(16) unsigned char k_lds[64 * 128];
  __shared__ __align__(16) unsigned char vt_lds[64 * 128];
  __shared__ __align__(16) unsigned char p_lds[4][16 * 128];

  const int tid  = threadIdx.x;
  const int lane = tid & 63;
  const int w    = tid >> 6;
  const int lr   = lane & 15;
  const int lg   = lane >> 4;
  const int swz  = (lr & 7) << 4;

  const int lb = blockIdx.x;
  const int e  = lb & 7;
  const int s  = lb >> 3;
  const int bh = e + 8 * (s >> 5);
  const int qs = s & 31;
  const int qt = (qs & 1) ? (NQT - 1 - (qs >> 1)) : (qs >> 1);
  const long base = (long)bh * (S_LEN * D_DIM);
  const int q0 = qt * 64;

  bf16x8 qf[2];
  {
    const float qsc = 0.125f * 1.44269504f;
    const float* qp = Qg + base + (q0 + w * 16 + lr) * D_DIM + lg * 8;
    #pragma unroll
    for (int c = 0; c < 2; ++c) {
      float4 f0 = *reinterpret_cast<const float4*>(qp + c * 32);
      float4 f1 = *reinterpret_cast<const float4*>(qp + c * 32 + 4);
      bf16x8 t;
      t[0]=(__bf16)(f0.x*qsc); t[1]=(__bf16)(f0.y*qsc);
      t[2]=(__bf16)(f0.z*qsc); t[3]=(__bf16)(f0.w*qsc);
      t[4]=(__bf16)(f1.x*qsc); t[5]=(__bf16)(f1.y*qsc);
      t[6]=(__bf16)(f1.z*qsc); t[7]=(__bf16)(f1.w*qsc);
      qf[c] = t;
    }
  }
  bf16x8 onesf;
  #pragma unroll
  for (int j = 0; j < 8; ++j) onesf[j] = (lr == 0) ? (__bf16)1.0f : (__bf16)0.0f;

  f32x4 po[4], pl;
  float m_run = -1e30f;
  #pragma unroll
  for (int j = 0; j < 4; ++j) po[j] = (f32x4){0.f,0.f,0.f,0.f};
  pl = (f32x4){0.f,0.f,0.f,0.f};

  float4 kreg[4];
  float  vreg[16];
  const int d_ = lane;
  const int kb = w;

  auto load_regs = [&](int kt) {
    const float* kg = Kg + base + kt * (64 * D_DIM);
    #pragma unroll
    for (int i = 0; i < 4; ++i) {
      int idx = tid + 256 * i;
      int r = idx >> 4, f4 = idx & 15;
      kreg[i] = *reinterpret_cast<const float4*>(kg + r * 64 + f4 * 4);
    }
    const float* vg = Vg + base + kt * (64 * D_DIM);
    #pragma unroll
    for (int j = 0; j < 8; ++j) {
      vreg[j]     = vg[(kb * 8 + j) * 64 + d_];
      vreg[8 + j] = vg[((kb + 4) * 8 + j) * 64 + d_];
    }
  };
  auto write_buf = [&]() {
    #pragma unroll
    for (int i = 0; i < 4; ++i) {
      int idx = tid + 256 * i;
      int r = idx >> 4, f4 = idx & 15;
      bf16x4 t;
      t[0]=(__bf16)kreg[i].x; t[1]=(__bf16)kreg[i].y;
      t[2]=(__bf16)kreg[i].z; t[3]=(__bf16)kreg[i].w;
      int b = r * 128 + ((f4 * 8) ^ ((r & 7) << 4));
      *reinterpret_cast<bf16x4*>(&k_lds[b]) = t;
    }
    bf16x8 t0, t1;
    #pragma unroll
    for (int j = 0; j < 8; ++j) { t0[j] = (__bf16)vreg[j]; t1[j] = (__bf16)vreg[8+j]; }
    int b0 = d_ * 128 + ((kb * 16) ^ ((d_ & 7) << 4));
    int b1 = d_ * 128 + (((kb + 4) * 16) ^ ((d_ & 7) << 4));
    *reinterpret_cast<bf16x8*>(&vt_lds[b0]) = t0;
    *reinterpret_cast<bf16x8*>(&vt_lds[b1]) = t1;
  };

  load_regs(0);
  write_buf();
  __syncthreads();

  for (int kt = 0; kt <= qt; ++kt) {
    const bool last = (kt == qt);
    if (!last) load_regs(kt + 1);

    f32x4 sa[4];
    #pragma unroll
    for (int ct = 0; ct < 4; ++ct) sa[ct] = (f32x4){0.f,0.f,0.f,0.f};
    #pragma unroll
    for (int ct = 0; ct < 4; ++ct) {
      #pragma unroll
      for (int c = 0; c < 2; ++c) {
        int b = (ct * 16 + lr) * 128 + ((lg * 16 + c * 64) ^ swz);
        bf16x8 kf = *reinterpret_cast<const bf16x8*>(&k_lds[b]);
        sa[ct] = __builtin_amdgcn_mfma_f32_16x16x32_bf16(kf, qf[c], sa[ct], 0, 0, 0);
      }
    }
    if (last) {
      #pragma unroll
      for (int ct = 0; ct < 4; ++ct)
        #pragma unroll
        for (int j = 0; j < 4; ++j)
          if (ct * 16 + lg * 4 + j > w * 16 + lr) sa[ct][j] = -1e30f;
    }
    float rmax = sa[0][0];
    #pragma unroll
    for (int ct = 0; ct < 4; ++ct)
      #pragma unroll
      for (int j = 0; j < 4; ++j) rmax = fmaxf(rmax, sa[ct][j]);
    rmax = fmaxf(rmax, __shfl_xor(rmax, 16));
    rmax = fmaxf(rmax, __shfl_xor(rmax, 32));
    float mn    = fmaxf(m_run, rmax);
    float alpha = exp2f(m_run - mn);
    m_run = mn;
    #pragma unroll
    for (int ct = 0; ct < 4; ++ct) {
      bf16x4 t;
      #pragma unroll
      for (int j = 0; j < 4; ++j) t[j] = (__bf16)exp2f(sa[ct][j] - mn);
      int b = lr * 128 + ((ct * 32 + lg * 8) ^ swz);
      *reinterpret_cast<bf16x4*>(&p_lds[w][b]) = t;
    }
    float aj[4];
    #pragma unroll
    for (int j = 0; j < 4; ++j) aj[j] = __shfl(alpha, (lane & 48) | (lg * 4 + j));
    #pragma unroll
    for (int j = 0; j < 4; ++j) {
      pl[j] *= aj[j];
      #pragma unroll
      for (int dt = 0; dt < 4; ++dt) po[dt][j] *= aj[j];
    }
    #pragma unroll
    for (int c = 0; c < 2; ++c) {
      int ab = lr * 128 + ((lg * 16 + c * 64) ^ swz);
      bf16x8 pa = *reinterpret_cast<const bf16x8*>(&p_lds[w][ab]);
      pl = __builtin_amdgcn_mfma_f32_16x16x32_bf16(pa, onesf, pl, 0, 0, 0);
      #pragma unroll
      for (int dt = 0; dt < 4; ++dt) {
        int vb_ = (dt * 16 + lr) * 128 + ((lg * 16 + c * 64) ^ swz);
        bf16x8 vb = *reinterpret_cast<const bf16x8*>(&vt_lds[vb_]);
        po[dt] = __builtin_amdgcn_mfma_f32_16x16x32_bf16(pa, vb, po[dt], 0, 0, 0);
      }
    }
    if (!last) {
      __syncthreads();
      write_buf();
      __syncthreads();
    }
  }
  #pragma unroll
  for (int j = 0; j < 4; ++j) {
    float lv  = __shfl(pl[j], lane & 48);
    float inv = 1.0f / lv;
    int row = q0 + w * 16 + lg * 4 + j;
    #pragma unroll
    for (int dt = 0; dt < 4; ++dt)
      Og[base + row * D_DIM + dt * 16 + lr] = po[dt][j] * inv;
  }
}

extern "C" void kernel_launch(void* const* d_in, const int* in_sizes, int n_in,
                              void* d_out, int out_size, void* d_ws, size_t ws_size,
                              hipStream_t stream) {
  const float* V = (const float*)d_in[0];
  const float* Q = (const float*)d_in[1];
  const float* K = (const float*)d_in[2];
  float* O = (float*)d_out;
  const size_t need = (size_t)2 * 32 * 32 * 8192;  // Kb + Vt = 16 MB
  if (ws_size >= need) {
    unsigned char* Kb = (unsigned char*)d_ws;
    unsigned char* Vt = Kb + (size_t)32 * 32 * 8192;
    preprocess_kernel<<<dim3(1024), dim3(256), 0, stream>>>(K, V, Kb, Vt);
    attn_fwd_fast<<<dim3(1024), dim3(256), 0, stream>>>(Q, Kb, Vt, O);
  } else {
    attn_fwd_fallback<<<dim3(1024), dim3(256), 0, stream>>>(V, Q, K, O);
  }
}

// Round 7
// 74.196 us; speedup vs baseline: 1.5032x; 1.1831x over previous
//
#include <hip/hip_runtime.h>
#include <hip/hip_bf16.h>

typedef __bf16 bf16x8 __attribute__((ext_vector_type(8)));
typedef __bf16 bf16x4 __attribute__((ext_vector_type(4)));
typedef float f32x4 __attribute__((ext_vector_type(4)));

#define S_LEN 2048
#define D_DIM 64
#define NQT   32

// ---------------- preprocess ----------------
// Kb per (bh,kt) tile: 512 x 16B chunks in MFMA A-frag order:
//   chunk idx = (ct*2+c)*64 + lane ; holds K[ct*16 + (lane&15)][c*32 + (lane>>4)*8 .. +7] bf16
// Vt per tile: chunk idx = (dt*2+c)*64 + lane ; holds V[k = c*32 + (lane>>4)*8 + j][dt*16 + (lane&15)]
// -> main kernel loads fragments global->VGPR fully coalesced (64 lanes x 16B = 1KB).
__global__ __launch_bounds__(256) void preprocess_kernel(
    const float* __restrict__ Kg, const float* __restrict__ Vg,
    unsigned char* __restrict__ Kb, unsigned char* __restrict__ Vt) {
  __shared__ float buf[4096];  // 16 KB fp32 tile
  const int tid  = threadIdx.x;
  const int tile = blockIdx.x;     // bh*32 + kt
  const float* kg = Kg + (long)tile * 4096;
  const float* vg = Vg + (long)tile * 4096;
  unsigned char* kb = Kb + (long)tile * 8192;
  unsigned char* vt = Vt + (long)tile * 8192;

  // ---- K ----
  #pragma unroll
  for (int i = 0; i < 4; ++i) {
    int idx = tid + 256 * i;
    *reinterpret_cast<float4*>(buf + idx * 4) =
        *reinterpret_cast<const float4*>(kg + idx * 4);
  }
  __syncthreads();
  #pragma unroll
  for (int s = 0; s < 2; ++s) {
    int idx = tid + 256 * s;           // 0..511
    int l  = idx & 63;
    int c  = (idx >> 6) & 1;
    int ct = idx >> 7;
    int r  = ct * 16 + (l & 15);
    int d0 = c * 32 + (l >> 4) * 8;
    bf16x8 t;
    #pragma unroll
    for (int j = 0; j < 8; ++j) t[j] = (__bf16)buf[r * 64 + d0 + j];
    *reinterpret_cast<bf16x8*>(kb + idx * 16) = t;
  }
  __syncthreads();
  // ---- V ----
  #pragma unroll
  for (int i = 0; i < 4; ++i) {
    int idx = tid + 256 * i;
    *reinterpret_cast<float4*>(buf + idx * 4) =
        *reinterpret_cast<const float4*>(vg + idx * 4);
  }
  __syncthreads();
  #pragma unroll
  for (int s = 0; s < 2; ++s) {
    int idx = tid + 256 * s;
    int l  = idx & 63;
    int c  = (idx >> 6) & 1;
    int dt = idx >> 7;
    int d  = dt * 16 + (l & 15);
    int k0 = c * 32 + (l >> 4) * 8;
    bf16x8 t;
    #pragma unroll
    for (int j = 0; j < 8; ++j) t[j] = (__bf16)buf[(k0 + j) * 64 + d];
    *reinterpret_cast<bf16x8*>(vt + idx * 16) = t;
  }
}

// ---------------- main: barrier-free flash-attn; K/V fragments global->VGPR ----------------
__global__ __launch_bounds__(256) void attn_fwd_reg(
    const float* __restrict__ Qg, const unsigned char* __restrict__ Kb,
    const unsigned char* __restrict__ Vt, float* __restrict__ Og) {
  __shared__ __align__(16) unsigned char p_lds[4][2048];  // per-wave P buffer only

  const int tid  = threadIdx.x;
  const int lane = tid & 63;
  const int w    = tid >> 6;
  const int lr   = lane & 15;
  const int lg   = lane >> 4;
  const int swz  = (lr & 7) << 4;

  // XCD-clustered bh + long/short interleave
  const int lb = blockIdx.x;
  const int e  = lb & 7;
  const int s  = lb >> 3;
  const int bh = e + 8 * (s >> 5);
  const int qs = s & 31;
  const int qt = (qs & 1) ? (NQT - 1 - (qs >> 1)) : (qs >> 1);
  const long base = (long)bh * (S_LEN * D_DIM);
  const int q0 = qt * 64;

  // Q fragment (B-operand), prescaled by 1/8 * log2(e)
  bf16x8 qf[2];
  {
    const float qsc = 0.125f * 1.44269504f;
    const float* qp = Qg + base + (q0 + w * 16 + lr) * D_DIM + lg * 8;
    #pragma unroll
    for (int c = 0; c < 2; ++c) {
      float4 f0 = *reinterpret_cast<const float4*>(qp + c * 32);
      float4 f1 = *reinterpret_cast<const float4*>(qp + c * 32 + 4);
      bf16x8 t;
      t[0]=(__bf16)(f0.x*qsc); t[1]=(__bf16)(f0.y*qsc);
      t[2]=(__bf16)(f0.z*qsc); t[3]=(__bf16)(f0.w*qsc);
      t[4]=(__bf16)(f1.x*qsc); t[5]=(__bf16)(f1.y*qsc);
      t[6]=(__bf16)(f1.z*qsc); t[7]=(__bf16)(f1.w*qsc);
      qf[c] = t;
    }
  }

  f32x4 po[4];
  #pragma unroll
  for (int j = 0; j < 4; ++j) po[j] = (f32x4){0.f,0.f,0.f,0.f};
  float m_run = -1e30f;   // per-lane == per-q-row (swapped layout)
  float l_run = 0.f;

  const unsigned char* kb_bh = Kb + ((long)bh << 5) * 8192 + lane * 16;
  const unsigned char* vt_bh = Vt + ((long)bh << 5) * 8192 + lane * 16;

  bf16x8 kfr[8];  // [ct*2+c] : whole K tile as A-frags
  bf16x8 vfr[8];  // [dt*2+c] : whole V^T tile as B-frags

  auto ldK = [&](int kt) {
    const unsigned char* p = kb_bh + (long)kt * 8192;
    #pragma unroll
    for (int f = 0; f < 8; ++f)
      kfr[f] = *reinterpret_cast<const bf16x8*>(p + f * 1024);
  };
  auto ldV = [&](int kt) {
    const unsigned char* p = vt_bh + (long)kt * 8192;
    #pragma unroll
    for (int f = 0; f < 8; ++f)
      vfr[f] = *reinterpret_cast<const bf16x8*>(p + f * 1024);
  };

  ldK(0);
  ldV(0);

  for (int kt = 0; kt <= qt; ++kt) {
    const bool last = (kt == qt);

    // S^T via mfma(K, Q): sa[ct][j] = S[q = w*16+lr][k = ct*16 + lg*4 + j]
    f32x4 sa[4];
    #pragma unroll
    for (int ct = 0; ct < 4; ++ct) sa[ct] = (f32x4){0.f,0.f,0.f,0.f};
    __builtin_amdgcn_s_setprio(1);
    #pragma unroll
    for (int ct = 0; ct < 4; ++ct)
      #pragma unroll
      for (int c = 0; c < 2; ++c)
        sa[ct] = __builtin_amdgcn_mfma_f32_16x16x32_bf16(kfr[ct*2+c], qf[c], sa[ct], 0, 0, 0);
    __builtin_amdgcn_s_setprio(0);

    if (!last) ldK(kt + 1);   // prefetch next K into same regs (WAR ok; lands during softmax+PV)

    if (last) {  // causal mask, diag tile only
      #pragma unroll
      for (int ct = 0; ct < 4; ++ct)
        #pragma unroll
        for (int j = 0; j < 4; ++j)
          if (ct * 16 + lg * 4 + j > w * 16 + lr) sa[ct][j] = -1e30f;
    }

    // row max: 15 in-lane fmax + 2 shuffles
    float rmax = sa[0][0];
    #pragma unroll
    for (int ct = 0; ct < 4; ++ct)
      #pragma unroll
      for (int j = 0; j < 4; ++j) rmax = fmaxf(rmax, sa[ct][j]);
    rmax = fmaxf(rmax, __shfl_xor(rmax, 16));
    rmax = fmaxf(rmax, __shfl_xor(rmax, 32));

    // defer-max (T13): rescale only when running max grew by > 8 (exp2 units)
    if (__any(rmax > m_run + 8.0f)) {
      float mn    = fmaxf(m_run, rmax);
      float alpha = exp2f(m_run - mn);
      m_run = mn;
      l_run *= alpha;
      float aj[4];
      #pragma unroll
      for (int j = 0; j < 4; ++j) aj[j] = __shfl(alpha, (lane & 48) | (lg * 4 + j));
      #pragma unroll
      for (int j = 0; j < 4; ++j)
        #pragma unroll
        for (int dt = 0; dt < 4; ++dt) po[dt][j] *= aj[j];
    }

    // P = exp2(S' - m) -> per-wave LDS row lr (no barrier: wave-private buffer)
    float rowsum = 0.f;
    #pragma unroll
    for (int ct = 0; ct < 4; ++ct) {
      bf16x4 t;
      #pragma unroll
      for (int j = 0; j < 4; ++j) {
        float p = exp2f(sa[ct][j] - m_run);
        rowsum += p;
        t[j] = (__bf16)p;
      }
      int b = lr * 128 + ((ct * 32 + lg * 8) ^ swz);
      *reinterpret_cast<bf16x4*>(&p_lds[w][b]) = t;
    }
    rowsum += __shfl_xor(rowsum, 16);
    rowsum += __shfl_xor(rowsum, 32);
    l_run += rowsum;

    // O += P V
    __builtin_amdgcn_s_setprio(1);
    #pragma unroll
    for (int c = 0; c < 2; ++c) {
      int ab = lr * 128 + ((lg * 16 + c * 64) ^ swz);
      bf16x8 pa = *reinterpret_cast<const bf16x8*>(&p_lds[w][ab]);
      #pragma unroll
      for (int dt = 0; dt < 4; ++dt)
        po[dt] = __builtin_amdgcn_mfma_f32_16x16x32_bf16(pa, vfr[dt*2+c], po[dt], 0, 0, 0);
    }
    __builtin_amdgcn_s_setprio(0);

    if (!last) ldV(kt + 1);   // prefetch next V (lands during next iter's QK+softmax)
  }

  // epilogue: normalize, store fp32
  #pragma unroll
  for (int j = 0; j < 4; ++j) {
    float lv  = __shfl(l_run, (lane & 48) | (lg * 4 + j));
    float inv = 1.0f / lv;
    int row = q0 + w * 16 + lg * 4 + j;
    #pragma unroll
    for (int dt = 0; dt < 4; ++dt)
      Og[base + row * D_DIM + dt * 16 + lr] = po[dt][j] * inv;
  }
}

// ---------------- fallback (round-5 kernel) if ws too small ----------------
__global__ __launch_bounds__(256) void attn_fwd_fallback(
    const float* __restrict__ Vg, const float* __restrict__ Qg,
    const float* __restrict__ Kg, float* __restrict__ Og) {
  __shared__ __align__(16) unsigned char k_lds[64 * 128];
  __shared__ __align__(16) unsigned char vt_lds[64 * 128];
  __shared__ __align__(16) unsigned char p_lds[4][16 * 128];

  const int tid  = threadIdx.x;
  const int lane = tid & 63;
  const int w    = tid >> 6;
  const int lr   = lane & 15;
  const int lg   = lane >> 4;
  const int swz  = (lr & 7) << 4;

  const int lb = blockIdx.x;
  const int e  = lb & 7;
  const int s  = lb >> 3;
  const int bh = e + 8 * (s >> 5);
  const int qs = s & 31;
  const int qt = (qs & 1) ? (NQT - 1 - (qs >> 1)) : (qs >> 1);
  const long base = (long)bh * (S_LEN * D_DIM);
  const int q0 = qt * 64;

  bf16x8 qf[2];
  {
    const float qsc = 0.125f * 1.44269504f;
    const float* qp = Qg + base + (q0 + w * 16 + lr) * D_DIM + lg * 8;
    #pragma unroll
    for (int c = 0; c < 2; ++c) {
      float4 f0 = *reinterpret_cast<const float4*>(qp + c * 32);
      float4 f1 = *reinterpret_cast<const float4*>(qp + c * 32 + 4);
      bf16x8 t;
      t[0]=(__bf16)(f0.x*qsc); t[1]=(__bf16)(f0.y*qsc);
      t[2]=(__bf16)(f0.z*qsc); t[3]=(__bf16)(f0.w*qsc);
      t[4]=(__bf16)(f1.x*qsc); t[5]=(__bf16)(f1.y*qsc);
      t[6]=(__bf16)(f1.z*qsc); t[7]=(__bf16)(f1.w*qsc);
      qf[c] = t;
    }
  }
  bf16x8 onesf;
  #pragma unroll
  for (int j = 0; j < 8; ++j) onesf[j] = (lr == 0) ? (__bf16)1.0f : (__bf16)0.0f;

  f32x4 po[4], pl;
  float m_run = -1e30f;
  #pragma unroll
  for (int j = 0; j < 4; ++j) po[j] = (f32x4){0.f,0.f,0.f,0.f};
  pl = (f32x4){0.f,0.f,0.f,0.f};

  float4 kreg[4];
  float  vreg[16];
  const int d_ = lane;
  const int kb = w;

  auto load_regs = [&](int kt) {
    const float* kg = Kg + base + kt * (64 * D_DIM);
    #pragma unroll
    for (int i = 0; i < 4; ++i) {
      int idx = tid + 256 * i;
      int r = idx >> 4, f4 = idx & 15;
      kreg[i] = *reinterpret_cast<const float4*>(kg + r * 64 + f4 * 4);
    }
    const float* vg = Vg + base + kt * (64 * D_DIM);
    #pragma unroll
    for (int j = 0; j < 8; ++j) {
      vreg[j]     = vg[(kb * 8 + j) * 64 + d_];
      vreg[8 + j] = vg[((kb + 4) * 8 + j) * 64 + d_];
    }
  };
  auto write_buf = [&]() {
    #pragma unroll
    for (int i = 0; i < 4; ++i) {
      int idx = tid + 256 * i;
      int r = idx >> 4, f4 = idx & 15;
      bf16x4 t;
      t[0]=(__bf16)kreg[i].x; t[1]=(__bf16)kreg[i].y;
      t[2]=(__bf16)kreg[i].z; t[3]=(__bf16)kreg[i].w;
      int b = r * 128 + ((f4 * 8) ^ ((r & 7) << 4));
      *reinterpret_cast<bf16x4*>(&k_lds[b]) = t;
    }
    bf16x8 t0, t1;
    #pragma unroll
    for (int j = 0; j < 8; ++j) { t0[j] = (__bf16)vreg[j]; t1[j] = (__bf16)vreg[8+j]; }
    int b0 = d_ * 128 + ((kb * 16) ^ ((d_ & 7) << 4));
    int b1 = d_ * 128 + (((kb + 4) * 16) ^ ((d_ & 7) << 4));
    *reinterpret_cast<bf16x8*>(&vt_lds[b0]) = t0;
    *reinterpret_cast<bf16x8*>(&vt_lds[b1]) = t1;
  };

  load_regs(0);
  write_buf();
  __syncthreads();

  for (int kt = 0; kt <= qt; ++kt) {
    const bool last = (kt == qt);
    if (!last) load_regs(kt + 1);

    f32x4 sa[4];
    #pragma unroll
    for (int ct = 0; ct < 4; ++ct) sa[ct] = (f32x4){0.f,0.f,0.f,0.f};
    #pragma unroll
    for (int ct = 0; ct < 4; ++ct) {
      #pragma unroll
      for (int c = 0; c < 2; ++c) {
        int b = (ct * 16 + lr) * 128 + ((lg * 16 + c * 64) ^ swz);
        bf16x8 kf = *reinterpret_cast<const bf16x8*>(&k_lds[b]);
        sa[ct] = __builtin_amdgcn_mfma_f32_16x16x32_bf16(kf, qf[c], sa[ct], 0, 0, 0);
      }
    }
    if (last) {
      #pragma unroll
      for (int ct = 0; ct < 4; ++ct)
        #pragma unroll
        for (int j = 0; j < 4; ++j)
          if (ct * 16 + lg * 4 + j > w * 16 + lr) sa[ct][j] = -1e30f;
    }
    float rmax = sa[0][0];
    #pragma unroll
    for (int ct = 0; ct < 4; ++ct)
      #pragma unroll
      for (int j = 0; j < 4; ++j) rmax = fmaxf(rmax, sa[ct][j]);
    rmax = fmaxf(rmax, __shfl_xor(rmax, 16));
    rmax = fmaxf(rmax, __shfl_xor(rmax, 32));
    float mn    = fmaxf(m_run, rmax);
    float alpha = exp2f(m_run - mn);
    m_run = mn;
    #pragma unroll
    for (int ct = 0; ct < 4; ++ct) {
      bf16x4 t;
      #pragma unroll
      for (int j = 0; j < 4; ++j) t[j] = (__bf16)exp2f(sa[ct][j] - mn);
      int b = lr * 128 + ((ct * 32 + lg * 8) ^ swz);
      *reinterpret_cast<bf16x4*>(&p_lds[w][b]) = t;
    }
    float aj[4];
    #pragma unroll
    for (int j = 0; j < 4; ++j) aj[j] = __shfl(alpha, (lane & 48) | (lg * 4 + j));
    #pragma unroll
    for (int j = 0; j < 4; ++j) {
      pl[j] *= aj[j];
      #pragma unroll
      for (int dt = 0; dt < 4; ++dt) po[dt][j] *= aj[j];
    }
    #pragma unroll
    for (int c = 0; c < 2; ++c) {
      int ab = lr * 128 + ((lg * 16 + c * 64) ^ swz);
      bf16x8 pa = *reinterpret_cast<const bf16x8*>(&p_lds[w][ab]);
      pl = __builtin_amdgcn_mfma_f32_16x16x32_bf16(pa, onesf, pl, 0, 0, 0);
      #pragma unroll
      for (int dt = 0; dt < 4; ++dt) {
        int vb_ = (dt * 16 + lr) * 128 + ((lg * 16 + c * 64) ^ swz);
        bf16x8 vb = *reinterpret_cast<const bf16x8*>(&vt_lds[vb_]);
        po[dt] = __builtin_amdgcn_mfma_f32_16x16x32_bf16(pa, vb, po[dt], 0, 0, 0);
      }
    }
    if (!last) {
      __syncthreads();
      write_buf();
      __syncthreads();
    }
  }
  #pragma unroll
  for (int j = 0; j < 4; ++j) {
    float lv  = __shfl(pl[j], lane & 48);
    float inv = 1.0f / lv;
    int row = q0 + w * 16 + lg * 4 + j;
    #pragma unroll
    for (int dt = 0; dt < 4; ++dt)
      Og[base + row * D_DIM + dt * 16 + lr] = po[dt][j] * inv;
  }
}

extern "C" void kernel_launch(void* const* d_in, const int* in_sizes, int n_in,
                              void* d_out, int out_size, void* d_ws, size_t ws_size,
                              hipStream_t stream) {
  const float* V = (const float*)d_in[0];
  const float* Q = (const float*)d_in[1];
  const float* K = (const float*)d_in[2];
  float* O = (float*)d_out;
  const size_t need = (size_t)2 * 32 * 32 * 8192;  // Kb + Vt = 16 MB
  if (ws_size >= need) {
    unsigned char* Kb = (unsigned char*)d_ws;
    unsigned char* Vt = Kb + (size_t)32 * 32 * 8192;
    preprocess_kernel<<<dim3(1024), dim3(256), 0, stream>>>(K, V, Kb, Vt);
    attn_fwd_reg<<<dim3(1024), dim3(256), 0, stream>>>(Q, Kb, Vt, O);
  } else {
    attn_fwd_fallback<<<dim3(1024), dim3(256), 0, stream>>>(V, Q, K, O);
  }
}

// Round 8
// 65.015 us; speedup vs baseline: 1.7155x; 1.1412x over previous
//
#include <hip/hip_runtime.h>
#include <hip/hip_bf16.h>

typedef __bf16 bf16x8 __attribute__((ext_vector_type(8)));
typedef __bf16 bf16x4 __attribute__((ext_vector_type(4)));
typedef float f32x4 __attribute__((ext_vector_type(4)));

#define S_LEN 2048
#define D_DIM 64
#define NQT   32

// ---------------- preprocess ----------------
// Kb per (bh,kt) tile: 512 x 16B chunks in MFMA A-frag order:
//   chunk idx = (ct*2+c)*64 + lane ; holds K[ct*16 + (lane&15)][c*32 + (lane>>4)*8 .. +7] bf16
// Vt per tile: chunk idx = (dt*2+c)*64 + lane ; holds V[k = c*32 + (lane>>4)*8 + j][dt*16 + (lane&15)]
__global__ __launch_bounds__(256) void preprocess_kernel(
    const float* __restrict__ Kg, const float* __restrict__ Vg,
    unsigned char* __restrict__ Kb, unsigned char* __restrict__ Vt) {
  __shared__ float buf[4096];  // 16 KB fp32 tile
  const int tid  = threadIdx.x;
  const int tile = blockIdx.x;     // bh*32 + kt
  const float* kg = Kg + (long)tile * 4096;
  const float* vg = Vg + (long)tile * 4096;
  unsigned char* kb = Kb + (long)tile * 8192;
  unsigned char* vt = Vt + (long)tile * 8192;

  #pragma unroll
  for (int i = 0; i < 4; ++i) {
    int idx = tid + 256 * i;
    *reinterpret_cast<float4*>(buf + idx * 4) =
        *reinterpret_cast<const float4*>(kg + idx * 4);
  }
  __syncthreads();
  #pragma unroll
  for (int s = 0; s < 2; ++s) {
    int idx = tid + 256 * s;           // 0..511
    int l  = idx & 63;
    int c  = (idx >> 6) & 1;
    int ct = idx >> 7;
    int r  = ct * 16 + (l & 15);
    int d0 = c * 32 + (l >> 4) * 8;
    bf16x8 t;
    #pragma unroll
    for (int j = 0; j < 8; ++j) t[j] = (__bf16)buf[r * 64 + d0 + j];
    *reinterpret_cast<bf16x8*>(kb + idx * 16) = t;
  }
  __syncthreads();
  #pragma unroll
  for (int i = 0; i < 4; ++i) {
    int idx = tid + 256 * i;
    *reinterpret_cast<float4*>(buf + idx * 4) =
        *reinterpret_cast<const float4*>(vg + idx * 4);
  }
  __syncthreads();
  #pragma unroll
  for (int s = 0; s < 2; ++s) {
    int idx = tid + 256 * s;
    int l  = idx & 63;
    int c  = (idx >> 6) & 1;
    int dt = idx >> 7;
    int d  = dt * 16 + (l & 15);
    int k0 = c * 32 + (l >> 4) * 8;
    bf16x8 t;
    #pragma unroll
    for (int j = 0; j < 8; ++j) t[j] = (__bf16)buf[(k0 + j) * 64 + d];
    *reinterpret_cast<bf16x8*>(vt + idx * 16) = t;
  }
}

// ---------------- main: split-K flash-attn ----------------
// Block = 16 q-rows, 4 waves; wave w handles k-tiles w, w+4, w+8, ... (private
// m/l/O partials, per-tile code identical to r7), then a once-per-block LDS
// merge: O = sum_w exp2(m_w - M) O_w, normalized by the merged l.
__global__ __launch_bounds__(256) void attn_fwd_split(
    const float* __restrict__ Qg, const unsigned char* __restrict__ Kb,
    const unsigned char* __restrict__ Vt, float* __restrict__ Og) {
  __shared__ __align__(16) union {
    unsigned char p[4][2048];      // per-wave P buffer (loop phase)
    struct {
      float o[4][16][68];          // per-wave O partial (merge phase; 68 = pad)
      float m[4][16];
      float l[4][16];
    } mg;
  } sm;

  const int tid  = threadIdx.x;
  const int lane = tid & 63;
  const int w    = tid >> 6;
  const int lr   = lane & 15;
  const int lg   = lane >> 4;
  const int swz  = (lr & 7) << 4;

  // decode: XCD-clustered bh (4 bh per XCD), longest q-groups first
  const int lb = blockIdx.x;            // 0..4095
  const int e  = lb & 7;                // XCD
  const int s  = lb >> 3;               // 0..511
  const int bh = e + 8 * (s >> 7);      // 4 bh per XCD
  const int qg = 127 - (s & 127);       // q-group 0..127 (16 rows), LPT order
  const long base = (long)bh * (S_LEN * D_DIM);
  const int q0 = qg * 16;
  const int NT = (qg >> 2) + 1;         // # of 64-wide k-tiles for these rows

  // Q fragment (B-operand), prescaled by 1/8 * log2(e); same for all 4 waves
  bf16x8 qf[2];
  {
    const float qsc = 0.125f * 1.44269504f;
    const float* qp = Qg + base + (q0 + lr) * D_DIM + lg * 8;
    #pragma unroll
    for (int c = 0; c < 2; ++c) {
      float4 f0 = *reinterpret_cast<const float4*>(qp + c * 32);
      float4 f1 = *reinterpret_cast<const float4*>(qp + c * 32 + 4);
      bf16x8 t;
      t[0]=(__bf16)(f0.x*qsc); t[1]=(__bf16)(f0.y*qsc);
      t[2]=(__bf16)(f0.z*qsc); t[3]=(__bf16)(f0.w*qsc);
      t[4]=(__bf16)(f1.x*qsc); t[5]=(__bf16)(f1.y*qsc);
      t[6]=(__bf16)(f1.z*qsc); t[7]=(__bf16)(f1.w*qsc);
      qf[c] = t;
    }
  }

  f32x4 po[4];
  #pragma unroll
  for (int j = 0; j < 4; ++j) po[j] = (f32x4){0.f,0.f,0.f,0.f};
  float m_run = -1e30f;   // per-lane == q-row lr (replicated across lg)
  float l_run = 0.f;

  const unsigned char* kb_bh = Kb + ((long)bh << 5) * 8192 + lane * 16;
  const unsigned char* vt_bh = Vt + ((long)bh << 5) * 8192 + lane * 16;

  bf16x8 kfr[8], vfr[8];
  auto ldK = [&](int kt) {
    const unsigned char* p = kb_bh + (long)kt * 8192;
    #pragma unroll
    for (int f = 0; f < 8; ++f)
      kfr[f] = *reinterpret_cast<const bf16x8*>(p + f * 1024);
  };
  auto ldV = [&](int kt) {
    const unsigned char* p = vt_bh + (long)kt * 8192;
    #pragma unroll
    for (int f = 0; f < 8; ++f)
      vfr[f] = *reinterpret_cast<const bf16x8*>(p + f * 1024);
  };

  if (w < NT) {
    ldK(w);
    ldV(w);
    for (int kt = w; kt < NT; kt += 4) {
      const bool more = (kt + 4 < NT);

      // S^T via mfma(K, Q): sa[ct][j] = S[q = q0+lr][k = kt*64 + ct*16 + lg*4 + j]
      f32x4 sa[4];
      #pragma unroll
      for (int ct = 0; ct < 4; ++ct) sa[ct] = (f32x4){0.f,0.f,0.f,0.f};
      __builtin_amdgcn_s_setprio(1);
      #pragma unroll
      for (int ct = 0; ct < 4; ++ct)
        #pragma unroll
        for (int c = 0; c < 2; ++c)
          sa[ct] = __builtin_amdgcn_mfma_f32_16x16x32_bf16(kfr[ct*2+c], qf[c], sa[ct], 0, 0, 0);
      __builtin_amdgcn_s_setprio(0);

      if (more) ldK(kt + 4);  // prefetch next K into same regs (lands under softmax+PV)

      if (kt == NT - 1) {     // causal mask: only the last tile can cross the diagonal
        #pragma unroll
        for (int ct = 0; ct < 4; ++ct)
          #pragma unroll
          for (int j = 0; j < 4; ++j)
            if (kt * 64 + ct * 16 + lg * 4 + j > q0 + lr) sa[ct][j] = -1e30f;
      }

      // row max: 15 in-lane fmax + 2 shuffles
      float rmax = sa[0][0];
      #pragma unroll
      for (int ct = 0; ct < 4; ++ct)
        #pragma unroll
        for (int j = 0; j < 4; ++j) rmax = fmaxf(rmax, sa[ct][j]);
      rmax = fmaxf(rmax, __shfl_xor(rmax, 16));
      rmax = fmaxf(rmax, __shfl_xor(rmax, 32));

      // defer-max: rescale only when running max grew by > 8 (exp2 units)
      if (__any(rmax > m_run + 8.0f)) {
        float mn    = fmaxf(m_run, rmax);
        float alpha = exp2f(m_run - mn);
        m_run = mn;
        l_run *= alpha;
        float aj[4];
        #pragma unroll
        for (int j = 0; j < 4; ++j) aj[j] = __shfl(alpha, (lane & 48) | (lg * 4 + j));
        #pragma unroll
        for (int j = 0; j < 4; ++j)
          #pragma unroll
          for (int dt = 0; dt < 4; ++dt) po[dt][j] *= aj[j];
      }

      // P = exp2(S' - m) -> per-wave LDS row lr (wave-private, no barrier)
      float rowsum = 0.f;
      #pragma unroll
      for (int ct = 0; ct < 4; ++ct) {
        bf16x4 t;
        #pragma unroll
        for (int j = 0; j < 4; ++j) {
          float p = exp2f(sa[ct][j] - m_run);
          rowsum += p;
          t[j] = (__bf16)p;
        }
        int b = lr * 128 + ((ct * 32 + lg * 8) ^ swz);
        *reinterpret_cast<bf16x4*>(&sm.p[w][b]) = t;
      }
      rowsum += __shfl_xor(rowsum, 16);
      rowsum += __shfl_xor(rowsum, 32);
      l_run += rowsum;

      // O += P V
      __builtin_amdgcn_s_setprio(1);
      #pragma unroll
      for (int c = 0; c < 2; ++c) {
        int ab = lr * 128 + ((lg * 16 + c * 64) ^ swz);
        bf16x8 pa = *reinterpret_cast<const bf16x8*>(&sm.p[w][ab]);
        #pragma unroll
        for (int dt = 0; dt < 4; ++dt)
          po[dt] = __builtin_amdgcn_mfma_f32_16x16x32_bf16(pa, vfr[dt*2+c], po[dt], 0, 0, 0);
      }
      __builtin_amdgcn_s_setprio(0);

      if (more) ldV(kt + 4);  // prefetch next V (lands under next QK+softmax)
    }
  }

  // ---- merge: combine 4 wave-partials ----
  __syncthreads();   // everyone done with sm.p
  #pragma unroll
  for (int dt = 0; dt < 4; ++dt)
    #pragma unroll
    for (int j = 0; j < 4; ++j)
      sm.mg.o[w][lg * 4 + j][dt * 16 + lr] = po[dt][j];
  if (lg == 0) {
    sm.mg.m[w][lr] = m_run;
    sm.mg.l[w][lr] = l_run;
  }
  __syncthreads();

  {
    const int q  = tid >> 4;          // 0..15
    const int d0 = (tid & 15) * 4;    // 0,4,..60
    float m0 = sm.mg.m[0][q], m1 = sm.mg.m[1][q];
    float m2 = sm.mg.m[2][q], m3 = sm.mg.m[3][q];
    float M  = fmaxf(fmaxf(m0, m1), fmaxf(m2, m3));
    float a0 = exp2f(m0 - M), a1 = exp2f(m1 - M);
    float a2 = exp2f(m2 - M), a3 = exp2f(m3 - M);
    float lsum = a0 * sm.mg.l[0][q] + a1 * sm.mg.l[1][q]
               + a2 * sm.mg.l[2][q] + a3 * sm.mg.l[3][q];
    float inv = 1.0f / lsum;
    float4 outv;
    #pragma unroll
    for (int i = 0; i < 4; ++i) {
      float acc = a0 * sm.mg.o[0][q][d0 + i] + a1 * sm.mg.o[1][q][d0 + i]
                + a2 * sm.mg.o[2][q][d0 + i] + a3 * sm.mg.o[3][q][d0 + i];
      (&outv.x)[i] = acc * inv;
    }
    *reinterpret_cast<float4*>(Og + base + (long)(q0 + q) * D_DIM + d0) = outv;
  }
}

// ---------------- fallback (round-5 kernel) if ws too small ----------------
__global__ __launch_bounds__(256) void attn_fwd_fallback(
    const float* __restrict__ Vg, const float* __restrict__ Qg,
    const float* __restrict__ Kg, float* __restrict__ Og) {
  __shared__ __align__(16) unsigned char k_lds[64 * 128];
  __shared__ __align__(16) unsigned char vt_lds[64 * 128];
  __shared__ __align__(16) unsigned char p_lds[4][16 * 128];

  const int tid  = threadIdx.x;
  const int lane = tid & 63;
  const int w    = tid >> 6;
  const int lr   = lane & 15;
  const int lg   = lane >> 4;
  const int swz  = (lr & 7) << 4;

  const int lb = blockIdx.x;
  const int e  = lb & 7;
  const int s  = lb >> 3;
  const int bh = e + 8 * (s >> 5);
  const int qs = s & 31;
  const int qt = (qs & 1) ? (NQT - 1 - (qs >> 1)) : (qs >> 1);
  const long base = (long)bh * (S_LEN * D_DIM);
  const int q0 = qt * 64;

  bf16x8 qf[2];
  {
    const float qsc = 0.125f * 1.44269504f;
    const float* qp = Qg + base + (q0 + w * 16 + lr) * D_DIM + lg * 8;
    #pragma unroll
    for (int c = 0; c < 2; ++c) {
      float4 f0 = *reinterpret_cast<const float4*>(qp + c * 32);
      float4 f1 = *reinterpret_cast<const float4*>(qp + c * 32 + 4);
      bf16x8 t;
      t[0]=(__bf16)(f0.x*qsc); t[1]=(__bf16)(f0.y*qsc);
      t[2]=(__bf16)(f0.z*qsc); t[3]=(__bf16)(f0.w*qsc);
      t[4]=(__bf16)(f1.x*qsc); t[5]=(__bf16)(f1.y*qsc);
      t[6]=(__bf16)(f1.z*qsc); t[7]=(__bf16)(f1.w*qsc);
      qf[c] = t;
    }
  }
  bf16x8 onesf;
  #pragma unroll
  for (int j = 0; j < 8; ++j) onesf[j] = (lr == 0) ? (__bf16)1.0f : (__bf16)0.0f;

  f32x4 po[4], pl;
  float m_run = -1e30f;
  #pragma unroll
  for (int j = 0; j < 4; ++j) po[j] = (f32x4){0.f,0.f,0.f,0.f};
  pl = (f32x4){0.f,0.f,0.f,0.f};

  float4 kreg[4];
  float  vreg[16];
  const int d_ = lane;
  const int kb = w;

  auto load_regs = [&](int kt) {
    const float* kg = Kg + base + kt * (64 * D_DIM);
    #pragma unroll
    for (int i = 0; i < 4; ++i) {
      int idx = tid + 256 * i;
      int r = idx >> 4, f4 = idx & 15;
      kreg[i] = *reinterpret_cast<const float4*>(kg + r * 64 + f4 * 4);
    }
    const float* vg = Vg + base + kt * (64 * D_DIM);
    #pragma unroll
    for (int j = 0; j < 8; ++j) {
      vreg[j]     = vg[(kb * 8 + j) * 64 + d_];
      vreg[8 + j] = vg[((kb + 4) * 8 + j) * 64 + d_];
    }
  };
  auto write_buf = [&]() {
    #pragma unroll
    for (int i = 0; i < 4; ++i) {
      int idx = tid + 256 * i;
      int r = idx >> 4, f4 = idx & 15;
      bf16x4 t;
      t[0]=(__bf16)kreg[i].x; t[1]=(__bf16)kreg[i].y;
      t[2]=(__bf16)kreg[i].z; t[3]=(__bf16)kreg[i].w;
      int b = r * 128 + ((f4 * 8) ^ ((r & 7) << 4));
      *reinterpret_cast<bf16x4*>(&k_lds[b]) = t;
    }
    bf16x8 t0, t1;
    #pragma unroll
    for (int j = 0; j < 8; ++j) { t0[j] = (__bf16)vreg[j]; t1[j] = (__bf16)vreg[8+j]; }
    int b0 = d_ * 128 + ((kb * 16) ^ ((d_ & 7) << 4));
    int b1 = d_ * 128 + (((kb + 4) * 16) ^ ((d_ & 7) << 4));
    *reinterpret_cast<bf16x8*>(&vt_lds[b0]) = t0;
    *reinterpret_cast<bf16x8*>(&vt_lds[b1]) = t1;
  };

  load_regs(0);
  write_buf();
  __syncthreads();

  for (int kt = 0; kt <= qt; ++kt) {
    const bool last = (kt == qt);
    if (!last) load_regs(kt + 1);

    f32x4 sa[4];
    #pragma unroll
    for (int ct = 0; ct < 4; ++ct) sa[ct] = (f32x4){0.f,0.f,0.f,0.f};
    #pragma unroll
    for (int ct = 0; ct < 4; ++ct) {
      #pragma unroll
      for (int c = 0; c < 2; ++c) {
        int b = (ct * 16 + lr) * 128 + ((lg * 16 + c * 64) ^ swz);
        bf16x8 kf = *reinterpret_cast<const bf16x8*>(&k_lds[b]);
        sa[ct] = __builtin_amdgcn_mfma_f32_16x16x32_bf16(kf, qf[c], sa[ct], 0, 0, 0);
      }
    }
    if (last) {
      #pragma unroll
      for (int ct = 0; ct < 4; ++ct)
        #pragma unroll
        for (int j = 0; j < 4; ++j)
          if (ct * 16 + lg * 4 + j > w * 16 + lr) sa[ct][j] = -1e30f;
    }
    float rmax = sa[0][0];
    #pragma unroll
    for (int ct = 0; ct < 4; ++ct)
      #pragma unroll
      for (int j = 0; j < 4; ++j) rmax = fmaxf(rmax, sa[ct][j]);
    rmax = fmaxf(rmax, __shfl_xor(rmax, 16));
    rmax = fmaxf(rmax, __shfl_xor(rmax, 32));
    float mn    = fmaxf(m_run, rmax);
    float alpha = exp2f(m_run - mn);
    m_run = mn;
    #pragma unroll
    for (int ct = 0; ct < 4; ++ct) {
      bf16x4 t;
      #pragma unroll
      for (int j = 0; j < 4; ++j) t[j] = (__bf16)exp2f(sa[ct][j] - mn);
      int b = lr * 128 + ((ct * 32 + lg * 8) ^ swz);
      *reinterpret_cast<bf16x4*>(&p_lds[w][b]) = t;
    }
    float aj[4];
    #pragma unroll
    for (int j = 0; j < 4; ++j) aj[j] = __shfl(alpha, (lane & 48) | (lg * 4 + j));
    #pragma unroll
    for (int j = 0; j < 4; ++j) {
      pl[j] *= aj[j];
      #pragma unroll
      for (int dt = 0; dt < 4; ++dt) po[dt][j] *= aj[j];
    }
    #pragma unroll
    for (int c = 0; c < 2; ++c) {
      int ab = lr * 128 + ((lg * 16 + c * 64) ^ swz);
      bf16x8 pa = *reinterpret_cast<const bf16x8*>(&p_lds[w][ab]);
      pl = __builtin_amdgcn_mfma_f32_16x16x32_bf16(pa, onesf, pl, 0, 0, 0);
      #pragma unroll
      for (int dt = 0; dt < 4; ++dt) {
        int vb_ = (dt * 16 + lr) * 128 + ((lg * 16 + c * 64) ^ swz);
        bf16x8 vb = *reinterpret_cast<const bf16x8*>(&vt_lds[vb_]);
        po[dt] = __builtin_amdgcn_mfma_f32_16x16x32_bf16(pa, vb, po[dt], 0, 0, 0);
      }
    }
    if (!last) {
      __syncthreads();
      write_buf();
      __syncthreads();
    }
  }
  #pragma unroll
  for (int j = 0; j < 4; ++j) {
    float lv  = __shfl(pl[j], lane & 48);
    float inv = 1.0f / lv;
    int row = q0 + w * 16 + lg * 4 + j;
    #pragma unroll
    for (int dt = 0; dt < 4; ++dt)
      Og[base + row * D_DIM + dt * 16 + lr] = po[dt][j] * inv;
  }
}

extern "C" void kernel_launch(void* const* d_in, const int* in_sizes, int n_in,
                              void* d_out, int out_size, void* d_ws, size_t ws_size,
                              hipStream_t stream) {
  const float* V = (const float*)d_in[0];
  const float* Q = (const float*)d_in[1];
  const float* K = (const float*)d_in[2];
  float* O = (float*)d_out;
  const size_t need = (size_t)2 * 32 * 32 * 8192;  // Kb + Vt = 16 MB
  if (ws_size >= need) {
    unsigned char* Kb = (unsigned char*)d_ws;
    unsigned char* Vt = Kb + (size_t)32 * 32 * 8192;
    preprocess_kernel<<<dim3(1024), dim3(256), 0, stream>>>(K, V, Kb, Vt);
    attn_fwd_split<<<dim3(4096), dim3(256), 0, stream>>>(Q, Kb, Vt, O);
  } else {
    attn_fwd_fallback<<<dim3(1024), dim3(256), 0, stream>>>(V, Q, K, O);
  }
}

// Round 9
// 63.907 us; speedup vs baseline: 1.7453x; 1.0173x over previous
//
#include <hip/hip_runtime.h>
#include <hip/hip_bf16.h>

typedef __bf16 bf16x8 __attribute__((ext_vector_type(8)));
typedef __bf16 bf16x4 __attribute__((ext_vector_type(4)));
typedef float f32x4 __attribute__((ext_vector_type(4)));

#define S_LEN 2048
#define D_DIM 64
#define NQT   32

// ---------------- preprocess ----------------
// Kb per (bh,kt) tile: 512 x 16B chunks in MFMA A-frag order:
//   chunk idx = (ct*2+c)*64 + lane ; holds K[ct*16 + (lane&15)][c*32 + (lane>>4)*8 .. +7] bf16
// Vt per tile: chunk idx = (dt*2+c)*64 + lane ; holds V[k = c*32 + (lane>>4)*8 + j][dt*16 + (lane&15)]
__global__ __launch_bounds__(256) void preprocess_kernel(
    const float* __restrict__ Kg, const float* __restrict__ Vg,
    unsigned char* __restrict__ Kb, unsigned char* __restrict__ Vt) {
  __shared__ float buf[4096];  // 16 KB fp32 tile
  const int tid  = threadIdx.x;
  const int tile = blockIdx.x;     // bh*32 + kt
  const float* kg = Kg + (long)tile * 4096;
  const float* vg = Vg + (long)tile * 4096;
  unsigned char* kb = Kb + (long)tile * 8192;
  unsigned char* vt = Vt + (long)tile * 8192;

  #pragma unroll
  for (int i = 0; i < 4; ++i) {
    int idx = tid + 256 * i;
    *reinterpret_cast<float4*>(buf + idx * 4) =
        *reinterpret_cast<const float4*>(kg + idx * 4);
  }
  __syncthreads();
  #pragma unroll
  for (int s = 0; s < 2; ++s) {
    int idx = tid + 256 * s;           // 0..511
    int l  = idx & 63;
    int c  = (idx >> 6) & 1;
    int ct = idx >> 7;
    int r  = ct * 16 + (l & 15);
    int d0 = c * 32 + (l >> 4) * 8;
    bf16x8 t;
    #pragma unroll
    for (int j = 0; j < 8; ++j) t[j] = (__bf16)buf[r * 64 + d0 + j];
    *reinterpret_cast<bf16x8*>(kb + idx * 16) = t;
  }
  __syncthreads();
  #pragma unroll
  for (int i = 0; i < 4; ++i) {
    int idx = tid + 256 * i;
    *reinterpret_cast<float4*>(buf + idx * 4) =
        *reinterpret_cast<const float4*>(vg + idx * 4);
  }
  __syncthreads();
  #pragma unroll
  for (int s = 0; s < 2; ++s) {
    int idx = tid + 256 * s;
    int l  = idx & 63;
    int c  = (idx >> 6) & 1;
    int dt = idx >> 7;
    int d  = dt * 16 + (l & 15);
    int k0 = c * 32 + (l >> 4) * 8;
    bf16x8 t;
    #pragma unroll
    for (int j = 0; j < 8; ++j) t[j] = (__bf16)buf[(k0 + j) * 64 + d];
    *reinterpret_cast<bf16x8*>(vt + idx * 16) = t;
  }
}

// ---------------- main: fully independent waves ----------------
// Block = 128 threads = 2 waves; each wave owns ONE 16-row q-group (adjacent
// LPT pair -> intra-block imbalance <= 1 tile). No barriers, no merge, no
// idle waves. Per-tile loop identical to r8 (reg-fragment K/V, swapped QK^T,
// in-lane softmax, defer-max).
__global__ __launch_bounds__(128) void attn_fwd_wave(
    const float* __restrict__ Qg, const unsigned char* __restrict__ Kb,
    const unsigned char* __restrict__ Vt, float* __restrict__ Og) {
  __shared__ __align__(16) unsigned char p_lds[2][2048];  // per-wave P buffer

  const int tid  = threadIdx.x;
  const int lane = tid & 63;
  const int w    = tid >> 6;   // wave 0..1
  const int lr   = lane & 15;
  const int lg   = lane >> 4;
  const int swz  = (lr & 7) << 4;

  // decode: XCD-clustered bh (4 bh per XCD), longest q-groups first (LPT)
  const int lb = blockIdx.x;            // 0..2047
  const int e  = lb & 7;                // XCD
  const int s  = lb >> 3;               // 0..255
  const int bh = e + 8 * (s >> 6);      // 4 bh per XCD
  const int qg = 127 - ((s & 63) * 2 + w);  // q-group 0..127, longest first
  const long base = (long)bh * (S_LEN * D_DIM);
  const int q0 = qg * 16;
  const int NT = (qg >> 2) + 1;         // # of 64-wide k-tiles

  // Q fragment (B-operand), prescaled by 1/8 * log2(e)
  bf16x8 qf[2];
  {
    const float qsc = 0.125f * 1.44269504f;
    const float* qp = Qg + base + (q0 + lr) * D_DIM + lg * 8;
    #pragma unroll
    for (int c = 0; c < 2; ++c) {
      float4 f0 = *reinterpret_cast<const float4*>(qp + c * 32);
      float4 f1 = *reinterpret_cast<const float4*>(qp + c * 32 + 4);
      bf16x8 t;
      t[0]=(__bf16)(f0.x*qsc); t[1]=(__bf16)(f0.y*qsc);
      t[2]=(__bf16)(f0.z*qsc); t[3]=(__bf16)(f0.w*qsc);
      t[4]=(__bf16)(f1.x*qsc); t[5]=(__bf16)(f1.y*qsc);
      t[6]=(__bf16)(f1.z*qsc); t[7]=(__bf16)(f1.w*qsc);
      qf[c] = t;
    }
  }

  f32x4 po[4];
  #pragma unroll
  for (int j = 0; j < 4; ++j) po[j] = (f32x4){0.f,0.f,0.f,0.f};
  float m_run = -1e30f;   // per-lane == q-row lr (replicated across lg)
  float l_run = 0.f;

  const unsigned char* kb_bh = Kb + ((long)bh << 5) * 8192 + lane * 16;
  const unsigned char* vt_bh = Vt + ((long)bh << 5) * 8192 + lane * 16;

  bf16x8 kfr[8], vfr[8];
  auto ldK = [&](int kt) {
    const unsigned char* p = kb_bh + (long)kt * 8192;
    #pragma unroll
    for (int f = 0; f < 8; ++f)
      kfr[f] = *reinterpret_cast<const bf16x8*>(p + f * 1024);
  };
  auto ldV = [&](int kt) {
    const unsigned char* p = vt_bh + (long)kt * 8192;
    #pragma unroll
    for (int f = 0; f < 8; ++f)
      vfr[f] = *reinterpret_cast<const bf16x8*>(p + f * 1024);
  };

  ldK(0);
  ldV(0);

  for (int kt = 0; kt < NT; ++kt) {
    const bool more = (kt + 1 < NT);

    // S^T via mfma(K, Q): sa[ct][j] = S[q = q0+lr][k = kt*64 + ct*16 + lg*4 + j]
    f32x4 sa[4];
    #pragma unroll
    for (int ct = 0; ct < 4; ++ct) sa[ct] = (f32x4){0.f,0.f,0.f,0.f};
    __builtin_amdgcn_s_setprio(1);
    #pragma unroll
    for (int ct = 0; ct < 4; ++ct)
      #pragma unroll
      for (int c = 0; c < 2; ++c)
        sa[ct] = __builtin_amdgcn_mfma_f32_16x16x32_bf16(kfr[ct*2+c], qf[c], sa[ct], 0, 0, 0);
    __builtin_amdgcn_s_setprio(0);

    if (more) ldK(kt + 1);  // prefetch next K into same regs (lands under softmax+PV)

    if (kt == NT - 1) {     // causal mask: only the last tile can cross the diagonal
      #pragma unroll
      for (int ct = 0; ct < 4; ++ct)
        #pragma unroll
        for (int j = 0; j < 4; ++j)
          if (kt * 64 + ct * 16 + lg * 4 + j > q0 + lr) sa[ct][j] = -1e30f;
    }

    // row max: max3-friendly tree + 2 shuffles
    float rmax;
    {
      float t0 = fmaxf(fmaxf(sa[0][0], sa[0][1]), fmaxf(sa[0][2], sa[0][3]));
      float t1 = fmaxf(fmaxf(sa[1][0], sa[1][1]), fmaxf(sa[1][2], sa[1][3]));
      float t2 = fmaxf(fmaxf(sa[2][0], sa[2][1]), fmaxf(sa[2][2], sa[2][3]));
      float t3 = fmaxf(fmaxf(sa[3][0], sa[3][1]), fmaxf(sa[3][2], sa[3][3]));
      rmax = fmaxf(fmaxf(t0, t1), fmaxf(t2, t3));
    }
    rmax = fmaxf(rmax, __shfl_xor(rmax, 16));
    rmax = fmaxf(rmax, __shfl_xor(rmax, 32));

    // defer-max: rescale only when running max grew by > 8 (exp2 units)
    if (__any(rmax > m_run + 8.0f)) {
      float mn    = fmaxf(m_run, rmax);
      float alpha = exp2f(m_run - mn);
      m_run = mn;
      l_run *= alpha;
      float aj[4];
      #pragma unroll
      for (int j = 0; j < 4; ++j) aj[j] = __shfl(alpha, (lane & 48) | (lg * 4 + j));
      #pragma unroll
      for (int j = 0; j < 4; ++j)
        #pragma unroll
        for (int dt = 0; dt < 4; ++dt) po[dt][j] *= aj[j];
    }

    // P = exp2(S' - m) -> per-wave LDS row lr (wave-private, no barrier)
    float rowsum = 0.f;
    #pragma unroll
    for (int ct = 0; ct < 4; ++ct) {
      bf16x4 t;
      #pragma unroll
      for (int j = 0; j < 4; ++j) {
        float p = exp2f(sa[ct][j] - m_run);
        rowsum += p;
        t[j] = (__bf16)p;
      }
      int b = lr * 128 + ((ct * 32 + lg * 8) ^ swz);
      *reinterpret_cast<bf16x4*>(&p_lds[w][b]) = t;
    }
    rowsum += __shfl_xor(rowsum, 16);
    rowsum += __shfl_xor(rowsum, 32);
    l_run += rowsum;

    // O += P V
    __builtin_amdgcn_s_setprio(1);
    #pragma unroll
    for (int c = 0; c < 2; ++c) {
      int ab = lr * 128 + ((lg * 16 + c * 64) ^ swz);
      bf16x8 pa = *reinterpret_cast<const bf16x8*>(&p_lds[w][ab]);
      #pragma unroll
      for (int dt = 0; dt < 4; ++dt)
        po[dt] = __builtin_amdgcn_mfma_f32_16x16x32_bf16(pa, vfr[dt*2+c], po[dt], 0, 0, 0);
    }
    __builtin_amdgcn_s_setprio(0);

    if (more) ldV(kt + 1);  // prefetch next V (lands under next QK+softmax)
  }

  // epilogue: normalize, store fp32
  #pragma unroll
  for (int j = 0; j < 4; ++j) {
    float lv  = __shfl(l_run, (lane & 48) | (lg * 4 + j));
    float inv = 1.0f / lv;
    int row = q0 + lg * 4 + j;
    #pragma unroll
    for (int dt = 0; dt < 4; ++dt)
      Og[base + (long)row * D_DIM + dt * 16 + lr] = po[dt][j] * inv;
  }
}

// ---------------- fallback (round-5 kernel) if ws too small ----------------
__global__ __launch_bounds__(256) void attn_fwd_fallback(
    const float* __restrict__ Vg, const float* __restrict__ Qg,
    const float* __restrict__ Kg, float* __restrict__ Og) {
  __shared__ __align__(16) unsigned char k_lds[64 * 128];
  __shared__ __align__(16) unsigned char vt_lds[64 * 128];
  __shared__ __align__(16) unsigned char p_lds[4][16 * 128];

  const int tid  = threadIdx.x;
  const int lane = tid & 63;
  const int w    = tid >> 6;
  const int lr   = lane & 15;
  const int lg   = lane >> 4;
  const int swz  = (lr & 7) << 4;

  const int lb = blockIdx.x;
  const int e  = lb & 7;
  const int s  = lb >> 3;
  const int bh = e + 8 * (s >> 5);
  const int qs = s & 31;
  const int qt = (qs & 1) ? (NQT - 1 - (qs >> 1)) : (qs >> 1);
  const long base = (long)bh * (S_LEN * D_DIM);
  const int q0 = qt * 64;

  bf16x8 qf[2];
  {
    const float qsc = 0.125f * 1.44269504f;
    const float* qp = Qg + base + (q0 + w * 16 + lr) * D_DIM + lg * 8;
    #pragma unroll
    for (int c = 0; c < 2; ++c) {
      float4 f0 = *reinterpret_cast<const float4*>(qp + c * 32);
      float4 f1 = *reinterpret_cast<const float4*>(qp + c * 32 + 4);
      bf16x8 t;
      t[0]=(__bf16)(f0.x*qsc); t[1]=(__bf16)(f0.y*qsc);
      t[2]=(__bf16)(f0.z*qsc); t[3]=(__bf16)(f0.w*qsc);
      t[4]=(__bf16)(f1.x*qsc); t[5]=(__bf16)(f1.y*qsc);
      t[6]=(__bf16)(f1.z*qsc); t[7]=(__bf16)(f1.w*qsc);
      qf[c] = t;
    }
  }
  bf16x8 onesf;
  #pragma unroll
  for (int j = 0; j < 8; ++j) onesf[j] = (lr == 0) ? (__bf16)1.0f : (__bf16)0.0f;

  f32x4 po[4], pl;
  float m_run = -1e30f;
  #pragma unroll
  for (int j = 0; j < 4; ++j) po[j] = (f32x4){0.f,0.f,0.f,0.f};
  pl = (f32x4){0.f,0.f,0.f,0.f};

  float4 kreg[4];
  float  vreg[16];
  const int d_ = lane;
  const int kb = w;

  auto load_regs = [&](int kt) {
    const float* kg = Kg + base + kt * (64 * D_DIM);
    #pragma unroll
    for (int i = 0; i < 4; ++i) {
      int idx = tid + 256 * i;
      int r = idx >> 4, f4 = idx & 15;
      kreg[i] = *reinterpret_cast<const float4*>(kg + r * 64 + f4 * 4);
    }
    const float* vg = Vg + base + kt * (64 * D_DIM);
    #pragma unroll
    for (int j = 0; j < 8; ++j) {
      vreg[j]     = vg[(kb * 8 + j) * 64 + d_];
      vreg[8 + j] = vg[((kb + 4) * 8 + j) * 64 + d_];
    }
  };
  auto write_buf = [&]() {
    #pragma unroll
    for (int i = 0; i < 4; ++i) {
      int idx = tid + 256 * i;
      int r = idx >> 4, f4 = idx & 15;
      bf16x4 t;
      t[0]=(__bf16)kreg[i].x; t[1]=(__bf16)kreg[i].y;
      t[2]=(__bf16)kreg[i].z; t[3]=(__bf16)kreg[i].w;
      int b = r * 128 + ((f4 * 8) ^ ((r & 7) << 4));
      *reinterpret_cast<bf16x4*>(&k_lds[b]) = t;
    }
    bf16x8 t0, t1;
    #pragma unroll
    for (int j = 0; j < 8; ++j) { t0[j] = (__bf16)vreg[j]; t1[j] = (__bf16)vreg[8+j]; }
    int b0 = d_ * 128 + ((kb * 16) ^ ((d_ & 7) << 4));
    int b1 = d_ * 128 + (((kb + 4) * 16) ^ ((d_ & 7) << 4));
    *reinterpret_cast<bf16x8*>(&vt_lds[b0]) = t0;
    *reinterpret_cast<bf16x8*>(&vt_lds[b1]) = t1;
  };

  load_regs(0);
  write_buf();
  __syncthreads();

  for (int kt = 0; kt <= qt; ++kt) {
    const bool last = (kt == qt);
    if (!last) load_regs(kt + 1);

    f32x4 sa[4];
    #pragma unroll
    for (int ct = 0; ct < 4; ++ct) sa[ct] = (f32x4){0.f,0.f,0.f,0.f};
    #pragma unroll
    for (int ct = 0; ct < 4; ++ct) {
      #pragma unroll
      for (int c = 0; c < 2; ++c) {
        int b = (ct * 16 + lr) * 128 + ((lg * 16 + c * 64) ^ swz);
        bf16x8 kf = *reinterpret_cast<const bf16x8*>(&k_lds[b]);
        sa[ct] = __builtin_amdgcn_mfma_f32_16x16x32_bf16(kf, qf[c], sa[ct], 0, 0, 0);
      }
    }
    if (last) {
      #pragma unroll
      for (int ct = 0; ct < 4; ++ct)
        #pragma unroll
        for (int j = 0; j < 4; ++j)
          if (ct * 16 + lg * 4 + j > w * 16 + lr) sa[ct][j] = -1e30f;
    }
    float rmax = sa[0][0];
    #pragma unroll
    for (int ct = 0; ct < 4; ++ct)
      #pragma unroll
      for (int j = 0; j < 4; ++j) rmax = fmaxf(rmax, sa[ct][j]);
    rmax = fmaxf(rmax, __shfl_xor(rmax, 16));
    rmax = fmaxf(rmax, __shfl_xor(rmax, 32));
    float mn    = fmaxf(m_run, rmax);
    float alpha = exp2f(m_run - mn);
    m_run = mn;
    #pragma unroll
    for (int ct = 0; ct < 4; ++ct) {
      bf16x4 t;
      #pragma unroll
      for (int j = 0; j < 4; ++j) t[j] = (__bf16)exp2f(sa[ct][j] - mn);
      int b = lr * 128 + ((ct * 32 + lg * 8) ^ swz);
      *reinterpret_cast<bf16x4*>(&p_lds[w][b]) = t;
    }
    float aj[4];
    #pragma unroll
    for (int j = 0; j < 4; ++j) aj[j] = __shfl(alpha, (lane & 48) | (lg * 4 + j));
    #pragma unroll
    for (int j = 0; j < 4; ++j) {
      pl[j] *= aj[j];
      #pragma unroll
      for (int dt = 0; dt < 4; ++dt) po[dt][j] *= aj[j];
    }
    #pragma unroll
    for (int c = 0; c < 2; ++c) {
      int ab = lr * 128 + ((lg * 16 + c * 64) ^ swz);
      bf16x8 pa = *reinterpret_cast<const bf16x8*>(&p_lds[w][ab]);
      pl = __builtin_amdgcn_mfma_f32_16x16x32_bf16(pa, onesf, pl, 0, 0, 0);
      #pragma unroll
      for (int dt = 0; dt < 4; ++dt) {
        int vb_ = (dt * 16 + lr) * 128 + ((lg * 16 + c * 64) ^ swz);
        bf16x8 vb = *reinterpret_cast<const bf16x8*>(&vt_lds[vb_]);
        po[dt] = __builtin_amdgcn_mfma_f32_16x16x32_bf16(pa, vb, po[dt], 0, 0, 0);
      }
    }
    if (!last) {
      __syncthreads();
      write_buf();
      __syncthreads();
    }
  }
  #pragma unroll
  for (int j = 0; j < 4; ++j) {
    float lv  = __shfl(pl[j], lane & 48);
    float inv = 1.0f / lv;
    int row = q0 + w * 16 + lg * 4 + j;
    #pragma unroll
    for (int dt = 0; dt < 4; ++dt)
      Og[base + row * D_DIM + dt * 16 + lr] = po[dt][j] * inv;
  }
}

extern "C" void kernel_launch(void* const* d_in, const int* in_sizes, int n_in,
                              void* d_out, int out_size, void* d_ws, size_t ws_size,
                              hipStream_t stream) {
  const float* V = (const float*)d_in[0];
  const float* Q = (const float*)d_in[1];
  const float* K = (const float*)d_in[2];
  float* O = (float*)d_out;
  const size_t need = (size_t)2 * 32 * 32 * 8192;  // Kb + Vt = 16 MB
  if (ws_size >= need) {
    unsigned char* Kb = (unsigned char*)d_ws;
    unsigned char* Vt = Kb + (size_t)32 * 32 * 8192;
    preprocess_kernel<<<dim3(1024), dim3(256), 0, stream>>>(K, V, Kb, Vt);
    attn_fwd_wave<<<dim3(2048), dim3(128), 0, stream>>>(Q, Kb, Vt, O);
  } else {
    attn_fwd_fallback<<<dim3(1024), dim3(256), 0, stream>>>(V, Q, K, O);
  }
}